// Round 7
// baseline (365.415 us; speedup 1.0000x reference)
//
#include <hip/hip_runtime.h>
#include <cmath>

typedef unsigned short u16;
typedef __bf16 bf16x8 __attribute__((ext_vector_type(8)));
typedef float f32x4 __attribute__((ext_vector_type(4)));

#define DEVI __device__ __forceinline__

DEVI float b2f(u16 u){ union{unsigned int i; float f;} v; v.i=(unsigned int)u<<16; return v.f; }
DEVI u16 f2b(float f){ union{unsigned int i; float f;} v; v.f=f;
    unsigned int r=(v.i+0x7FFFu+((v.i>>16)&1u))>>16; return (u16)r; }

DEVI void gload_lds16(const u16* g, u16* l){
    __builtin_amdgcn_global_load_lds((__attribute__((address_space(1))) void*)g,
                                     (__attribute__((address_space(3))) void*)l,
                                     16, 0, 0);
}

// ---------------------------------------------------------------------------
// fp32 -> bf16 elementwise (X ingest). 4 elems/thread.
// ---------------------------------------------------------------------------
__global__ __launch_bounds__(256)
void cvt_bf16(const float* __restrict__ in, u16* __restrict__ out)
{
    const int i = (blockIdx.x * 256 + threadIdx.x) * 4;
    float4 v = *(const float4*)&in[i];
    ushort4 o;
    o.x = f2b(v.x); o.y = f2b(v.y); o.z = f2b(v.z); o.w = f2b(v.w);
    *(ushort4*)&out[i] = o;
}

// ---------------------------------------------------------------------------
// fp32 [R,C] -> bf16 [C,R] transpose (weight ingest). 64x64 LDS tiles.
// ---------------------------------------------------------------------------
__global__ __launch_bounds__(256)
void cvt_transpose(const float* __restrict__ in, u16* __restrict__ out, int R, int C)
{
    __shared__ __align__(16) u16 tile[64*72];
    const int rb = blockIdx.x*64, cb = blockIdx.y*64;
    const int t = threadIdx.x;
    const int r = t >> 3, c0 = (t & 7) * 8;
    #pragma unroll
    for (int rr = 0; rr < 2; rr++) {
        const int row = r + rr*32;
        float4 a = *(const float4*)&in[(long)(rb + row)*C + cb + c0];
        float4 b = *(const float4*)&in[(long)(rb + row)*C + cb + c0 + 4];
        u16* tp = &tile[row*72 + c0];
        tp[0]=f2b(a.x); tp[1]=f2b(a.y); tp[2]=f2b(a.z); tp[3]=f2b(a.w);
        tp[4]=f2b(b.x); tp[5]=f2b(b.y); tp[6]=f2b(b.z); tp[7]=f2b(b.w);
    }
    __syncthreads();
    #pragma unroll
    for (int rr = 0; rr < 2; rr++) {
        const int cr = r + rr*32;
        u16 tmp[8];
        #pragma unroll
        for (int j = 0; j < 8; j++) tmp[j] = tile[(c0 + j)*72 + cr];
        *(uint4*)&out[(long)(cb + cr)*R + rb + c0] = *(uint4*)tmp;
    }
}

// ---------------------------------------------------------------------------
// GEMM: C[M,N] = A[M,K] @ Bt[N,K]^T + bias. bf16 in/out, fp32 accum.
// Tile BM x 128, BK=64 (two 32-wide panels). 4 waves.
// QUAD-XOR LDS swizzle (both-sides, rule #21): chunk slot l holds global
// (row l>>2, colchunk (l&3)^((l>>3)&3)). Staging quads stay contiguous
// (VMEM coalescing preserved); fragment read at fr*32 + (fq^((fr>>1)&3))*8
// covers all 8 bank-groups per octet -> zero LDS conflicts (verified r6:
// SQ_LDS_BANK_CONFLICT = 0).
// EPI: 0 = bias, 1 = bias+residual, 2 = bias+tanh-GELU,
//      3 = QKV split: cols<2048 -> C row-major (width 2048),
//          cols>=2048 (V) -> C2 = VT[b*16+h][d][tok] transposed.
// DBUF=1: double-buffered single-barrier K-loop.
// Round-6 lesson: BM=64x128 tile = 583 TF, limited by LDS traffic/FLOP
// (each A-row/B-col read by 2 waves; 48KB reads per block-K-step). The
// N=1024 GEMMs now use BM=128 (wave tile 64x64, 1.5x FLOP/LDS-byte,
// per-CU LDS traffic 144->96 KB/K-step) at 1 block/CU -- round 3 proved
// this kernel is occupancy-insensitive.
// ---------------------------------------------------------------------------
template<int EPI, int BM, int DBUF>
__global__ __launch_bounds__(256)
void gemm_bt(const u16* __restrict__ A, const u16* __restrict__ Bt,
             const float* __restrict__ bias, const u16* __restrict__ Res,
             u16* __restrict__ C, u16* __restrict__ C2, int M, int N, int K)
{
    constexpr int RM = BM / 32;
    constexpr int NA = (BM / 16) * 2 / 4;
    constexpr int ASZ = BM*64, BSZ = 128*64;
    __shared__ __align__(16) u16 As[(DBUF ? 2 : 1)*ASZ];
    __shared__ __align__(16) u16 Bs[(DBUF ? 2 : 1)*BSZ];
    const int tid  = threadIdx.x;
    const int wave = tid >> 6, lane = tid & 63;
    const int tm = blockIdx.x * BM, tn = blockIdx.y * 128;

    // staging: lane quad a fetches row a's 64B, 16B-chunks XOR-permuted
    const int rs = lane >> 2, cs = ((lane & 3) ^ ((lane >> 3) & 3)) * 8;
    const u16* gA[NA]; u16* lA[NA];
    #pragma unroll
    for (int i = 0; i < NA; i++) {
        const int c = wave + i*4;
        const int p = c / (BM/16), rb = c % (BM/16);
        gA[i] = A + (long)(tm + rb*16 + rs)*K + p*32 + cs;
        lA[i] = As + p*(BM*32) + rb*512;
    }
    const u16* gB[4]; u16* lB[4];
    #pragma unroll
    for (int i = 0; i < 4; i++) {
        const int c = wave + i*4;
        const int p = c >> 3, rb = c & 7;
        gB[i] = Bt + (long)(tn + rb*16 + rs)*K + p*32 + cs;
        lB[i] = Bs + p*(128*32) + rb*512;
    }

    const int wm = (wave >> 1) * (BM/2), wn = (wave & 1) * 64;
    const int fr = lane & 15, fq = lane >> 4;
    const int fs = (fq ^ ((fr >> 1) & 3)) * 8;   // swizzled 16B-slot within row

    f32x4 acc[RM][4] = {};

    if constexpr (DBUF) {
        const int nk = K >> 6;
        #pragma unroll
        for (int i = 0; i < NA; i++) gload_lds16(gA[i], lA[i]);
        #pragma unroll
        for (int i = 0; i < 4; i++)  gload_lds16(gB[i], lB[i]);
        for (int t = 0; t < nk; t++) {
            __syncthreads();      // drains tile-t loads (issued last iter); rendezvous
            if (t + 1 < nk) {     // prefetch t+1 overlaps compute of t
                const int nb = (t + 1) & 1;
                const int k0 = (t + 1) << 6;
                #pragma unroll
                for (int i = 0; i < NA; i++) gload_lds16(gA[i] + k0, lA[i] + nb*ASZ);
                #pragma unroll
                for (int i = 0; i < 4; i++)  gload_lds16(gB[i] + k0, lB[i] + nb*BSZ);
            }
            const u16* Ab = As + (t & 1)*ASZ;
            const u16* Bb = Bs + (t & 1)*BSZ;
            #pragma unroll
            for (int p = 0; p < 2; p++) {
                bf16x8 af[RM], bfr[4];
                #pragma unroll
                for (int i = 0; i < RM; i++)
                    af[i]  = *(const bf16x8*)&Ab[p*(BM*32) + (wm + i*16 + fr)*32 + fs];
                #pragma unroll
                for (int j = 0; j < 4; j++)
                    bfr[j] = *(const bf16x8*)&Bb[p*(128*32) + (wn + j*16 + fr)*32 + fs];
                #pragma unroll
                for (int i = 0; i < RM; i++)
                    #pragma unroll
                    for (int j = 0; j < 4; j++)
                        acc[i][j] = __builtin_amdgcn_mfma_f32_16x16x32_bf16(af[i], bfr[j], acc[i][j], 0, 0, 0);
            }
        }
    } else {
        for (int k0 = 0; k0 < K; k0 += 64) {
            __syncthreads();
            #pragma unroll
            for (int i = 0; i < NA; i++) gload_lds16(gA[i] + k0, lA[i]);
            #pragma unroll
            for (int i = 0; i < 4; i++)  gload_lds16(gB[i] + k0, lB[i]);
            __syncthreads();
            #pragma unroll
            for (int p = 0; p < 2; p++) {
                bf16x8 af[RM], bfr[4];
                #pragma unroll
                for (int i = 0; i < RM; i++)
                    af[i]  = *(const bf16x8*)&As[p*(BM*32) + (wm + i*16 + fr)*32 + fs];
                #pragma unroll
                for (int j = 0; j < 4; j++)
                    bfr[j] = *(const bf16x8*)&Bs[p*(128*32) + (wn + j*16 + fr)*32 + fs];
                #pragma unroll
                for (int i = 0; i < RM; i++)
                    #pragma unroll
                    for (int j = 0; j < 4; j++)
                        acc[i][j] = __builtin_amdgcn_mfma_f32_16x16x32_bf16(af[i], bfr[j], acc[i][j], 0, 0, 0);
            }
        }
    }

    #pragma unroll
    for (int i = 0; i < RM; i++) {
        const int row = tm + wm + i*16 + fq*4;
        #pragma unroll
        for (int j = 0; j < 4; j++) {
            const int col = tn + wn + j*16 + fr;
            const float bv = bias[col];
            if (EPI == 3 && col >= 2048) {
                const int hh = (col - 2048) >> 6, dd = (col - 2048) & 63;
                const int batch = row >> 11, tok = row & 2047;
                u16 pk[4];
                #pragma unroll
                for (int r = 0; r < 4; r++) pk[r] = f2b(acc[i][j][r] + bv);
                *(uint2*)&C2[((long)(batch*16 + hh)*64 + dd)*2048 + tok] = *(uint2*)pk;
            } else {
                const int cw = (EPI == 3) ? 2048 : N;
                #pragma unroll
                for (int r = 0; r < 4; r++) {
                    float v = acc[i][j][r] + bv;
                    const long idx = (long)(row + r)*cw + col;
                    if (EPI == 1) v += b2f(Res[idx]);
                    if (EPI == 2) {
                        const float u = v + 0.044715f*v*v*v;
                        const float t = exp2f(u * 2.302208f);
                        v = v * t * __builtin_amdgcn_rcpf(t + 1.f);
                    }
                    C[idx] = f2b(v);
                }
            }
        }
    }
}

// ---------------------------------------------------------------------------
// Flash attention v9, causal. PAIRED q-tiles + SPLIT-KEY wave groups +
// quad-XOR K/V LDS swizzle (same both-sides trick as the GEMM).
// Block = 512 threads = 2 groups x 4 waves; (pair, head, batch) grid 16x16x2.
// ---------------------------------------------------------------------------
__global__ __launch_bounds__(512)
void attn_kernel(const u16* __restrict__ QK, const u16* __restrict__ VT,
                 u16* __restrict__ O)
{
    constexpr float CS = 0.18033688011112042f;   // 0.125 * log2(e)
    __shared__ __align__(16) u16 smem[40960];

    const int tid = threadIdx.x, wave = tid >> 6, lane = tid & 63;
    const int grp = wave >> 2, wg = wave & 3;
    const int pair = blockIdx.x, h = blockIdx.y, b = blockIdx.z;
    const int fr = lane & 15, fq = lane >> 4;
    const long qkbase = (long)b*2048*2048;
    const long vtbase = (long)(b*16 + h)*64*2048;
    const int rs = lane >> 2, cs2 = ((lane & 3) ^ ((lane >> 3) & 3)) * 8;
    const int fs = (fq ^ ((fr >> 1) & 3)) * 8;
    const int sw = (fr & 7) * 8;
    const int KsBase = grp*8192;
    const int VsBase = 16384 + grp*8192;
    u16* pw = &smem[32768 + wave*1024];

    #define ISSUE(bf, k0)                                                      \
        _Pragma("unroll")                                                      \
        for (int i = 0; i < 2; i++) {                                          \
            const int c = wg + i*4;                                            \
            const int kp = c >> 2, krb = c & 3;                                \
            gload_lds16(QK + qkbase + (long)((k0) + krb*16 + rs)*2048          \
                           + 1024 + h*64 + kp*32 + cs2,                        \
                        &smem[KsBase + (bf)*4096 + kp*2048 + krb*512]);        \
            const int vp = c & 1, vrb = c >> 1;                                \
            gload_lds16(VT + vtbase + (long)(vrb*16 + rs)*2048                 \
                           + (k0) + vp*32 + cs2,                               \
                        &smem[VsBase + (bf)*4096 + vp*2048 + vrb*512]);        \
        }

    #pragma unroll 1
    for (int which = 0; which < 2; which++) {
        const int qt = which ? pair : (31 - pair);

        bf16x8 bq[2];
        #pragma unroll
        for (int ks = 0; ks < 2; ks++)
            bq[ks] = *(const bf16x8*)&QK[qkbase + (long)(qt*64 + wg*16 + fr)*2048
                                         + h*64 + ks*32 + fq*8];

        const int q_glob = qt*64 + wg*16 + fr;
        const int q_wmin = qt*64 + wg*16;
        f32x4 o[4] = {};
        float m_i = -1e30f, l_i = 0.f;
        const int nkt = qt + 1;
        const int nit = (nkt + 1) >> 1;
        const int myn = (nkt + 1 - grp) >> 1;

        if (which) __syncthreads();
        if (grp < nkt) { ISSUE(0, grp*64) }

        for (int it = 0; it < nit; it++) {
            const int kt = 2*it + grp;
            const int k0 = kt * 64;
            const int cur = it & 1;
            __syncthreads();
            if (kt + 2 < nkt) { ISSUE(cur ^ 1, k0 + 128) }

            if (it < myn) {
                f32x4 st[4];
                #pragma unroll
                for (int mt = 0; mt < 4; mt++) st[mt] = (f32x4){0.f,0.f,0.f,0.f};
                #pragma unroll
                for (int mt = 0; mt < 4; mt++)
                    #pragma unroll
                    for (int ks = 0; ks < 2; ks++) {
                        bf16x8 ak = *(const bf16x8*)&smem[KsBase + cur*4096 + ks*2048 + (mt*16 + fr)*32 + fs];
                        st[mt] = __builtin_amdgcn_mfma_f32_16x16x32_bf16(ak, bq[ks], st[mt], 0, 0, 0);
                    }

                float mx = -1e30f;
                if (k0 + 63 > q_wmin) {
                    #pragma unroll
                    for (int mt = 0; mt < 4; mt++)
                        #pragma unroll
                        for (int r = 0; r < 4; r++) {
                            const int key = k0 + mt*16 + fq*4 + r;
                            float v = st[mt][r];
                            if (key > q_glob) v = -1e30f;
                            st[mt][r] = v;
                            mx = fmaxf(mx, v);
                        }
                } else {
                    #pragma unroll
                    for (int mt = 0; mt < 4; mt++)
                        #pragma unroll
                        for (int r = 0; r < 4; r++) mx = fmaxf(mx, st[mt][r]);
                }
                mx = fmaxf(mx, __shfl_xor(mx, 16, 64));
                mx = fmaxf(mx, __shfl_xor(mx, 32, 64));

                if (mx > m_i + 44.357f) {
                    const float alpha = exp2f((m_i - mx) * CS);
                    #pragma unroll
                    for (int dt = 0; dt < 4; dt++)
                        #pragma unroll
                        for (int r = 0; r < 4; r++) o[dt][r] *= alpha;
                    l_i *= alpha;
                    m_i = mx;
                }
                const float nms = -m_i * CS;
                float ps = 0.f;
                #pragma unroll
                for (int mt = 0; mt < 4; mt++)
                    #pragma unroll
                    for (int r = 0; r < 4; r++) {
                        const float p = exp2f(fmaf(st[mt][r], CS, nms));
                        st[mt][r] = p; ps += p;
                    }
                ps += __shfl_xor(ps, 16, 64);
                ps += __shfl_xor(ps, 32, 64);
                l_i += ps;

                #pragma unroll
                for (int mt = 0; mt < 4; mt++)
                    #pragma unroll
                    for (int d = 0; d < 2; d++) {
                        unsigned pk;
                        asm("v_cvt_pk_bf16_f32 %0, %1, %2"
                            : "=v"(pk) : "v"(st[mt][2*d]), "v"(st[mt][2*d+1]));
                        *(unsigned*)&pw[fr*64 + ((mt*16 + fq*4 + 2*d) ^ sw)] = pk;
                    }
                __asm__ volatile("" ::: "memory");
                bf16x8 bp[2];
                #pragma unroll
                for (int kk = 0; kk < 2; kk++)
                    bp[kk] = *(const bf16x8*)&pw[fr*64 + ((kk*32 + fq*8) ^ sw)];
                #pragma unroll
                for (int dt = 0; dt < 4; dt++)
                    #pragma unroll
                    for (int kk = 0; kk < 2; kk++) {
                        bf16x8 av = *(const bf16x8*)&smem[VsBase + cur*4096 + kk*2048 + (dt*16 + fr)*32 + fs];
                        o[dt] = __builtin_amdgcn_mfma_f32_16x16x32_bf16(av, bp[kk], o[dt], 0, 0, 0);
                    }
                __asm__ volatile("" ::: "memory");
            }
        }

        __syncthreads();
        float* MB = (float*)&smem[8192];
        float* ML = (float*)&smem[24576];
        if (grp == 1) {
            #pragma unroll
            for (int dt = 0; dt < 4; dt++)
                *(f32x4*)&MB[(wg*64 + lane)*16 + dt*4] = o[dt];
            if (fq == 0) {
                ML[(wg*16 + fr)*2]     = m_i;
                ML[(wg*16 + fr)*2 + 1] = l_i;
            }
        }
        __syncthreads();
        if (grp == 0) {
            const float m1 = ML[(wg*16 + fr)*2];
            const float l1 = ML[(wg*16 + fr)*2 + 1];
            const float m  = fmaxf(m_i, m1);
            const float e0 = exp2f((m_i - m) * CS);
            const float e1 = exp2f((m1  - m) * CS);
            const float rl = __builtin_amdgcn_rcpf(l_i*e0 + l1*e1);
            const long orow = (long)b*2048 + qt*64 + wg*16 + fr;
            #pragma unroll
            for (int dt = 0; dt < 4; dt++) {
                f32x4 o1 = *(const f32x4*)&MB[(wg*64 + lane)*16 + dt*4];
                u16 pk[4];
                #pragma unroll
                for (int r = 0; r < 4; r++)
                    pk[r] = f2b((o[dt][r]*e0 + o1[r]*e1) * rl);
                *(uint2*)&O[orow*1024 + h*64 + dt*16 + fq*4] = *(uint2*)pk;
            }
        }
    }
    #undef ISSUE
}

// ---------------------------------------------------------------------------
// LayerNorm over 1024 cols; bf16 in, fp32 gamma/beta; OUTF32 selects output.
// ---------------------------------------------------------------------------
template<int OUTF32>
__global__ __launch_bounds__(256)
void ln_kernel(const u16* __restrict__ X, const float* __restrict__ G,
               const float* __restrict__ B, void* __restrict__ Yv)
{
    __shared__ float red[8];
    const int tid = threadIdx.x;
    const long row = blockIdx.x;
    const u16* x = X + row*1024;
    ushort4 u = *(const ushort4*)&x[tid*4];
    const float v0 = b2f(u.x), v1 = b2f(u.y), v2 = b2f(u.z), v3 = b2f(u.w);
    float s = v0+v1+v2+v3;
    float q = v0*v0+v1*v1+v2*v2+v3*v3;
    #pragma unroll
    for (int off = 32; off >= 1; off >>= 1) {
        s += __shfl_xor(s, off, 64);
        q += __shfl_xor(q, off, 64);
    }
    const int wv = tid >> 6;
    if ((tid & 63) == 0) { red[wv*2] = s; red[wv*2+1] = q; }
    __syncthreads();
    s = red[0]+red[2]+red[4]+red[6];
    q = red[1]+red[3]+red[5]+red[7];
    const float mu = s * (1.f/1024.f);
    const float rstd = rsqrtf(fmaxf(q*(1.f/1024.f) - mu*mu, 0.f) + 1e-5f);
    float4 g4 = *(const float4*)&G[tid*4];
    float4 b4 = *(const float4*)&B[tid*4];
    const float y0 = (v0-mu)*rstd*g4.x + b4.x;
    const float y1 = (v1-mu)*rstd*g4.y + b4.y;
    const float y2 = (v2-mu)*rstd*g4.z + b4.z;
    const float y3 = (v3-mu)*rstd*g4.w + b4.w;
    if (OUTF32) {
        float4 o = make_float4(y0, y1, y2, y3);
        *(float4*)&((float*)Yv)[row*1024 + tid*4] = o;
    } else {
        ushort4 o;
        o.x = f2b(y0); o.y = f2b(y1); o.z = f2b(y2); o.w = f2b(y3);
        *(ushort4*)&((u16*)Yv)[row*1024 + tid*4] = o;
    }
}

// ---------------------------------------------------------------------------
// Workspace (48 MiB of d_ws + d_out as W1T/W2T scratch), liveness-audited:
//   Xbf [0,8) | WqkvT [8,14) | WoT [14,16) | QK [16,32) | VT [32,40) |
//   AO [40,48) | S1 [16,24) after attn | H1 [0,8) after LN1 |
//   Gbuf [8,40) FF1..FF2 | S2 [40,48) | W1T/W2T in d_out (dead before LN2)
// ---------------------------------------------------------------------------
extern "C" void kernel_launch(void* const* d_in, const int* in_sizes, int n_in,
                              void* d_out, int out_size, void* d_ws, size_t ws_size,
                              hipStream_t stream)
{
    const float* X    = (const float*)d_in[0];
    const float* Wqkv = (const float*)d_in[1];
    const float* bqkv = (const float*)d_in[2];
    const float* Wo   = (const float*)d_in[3];
    const float* bo   = (const float*)d_in[4];
    const float* W1   = (const float*)d_in[5];
    const float* b1   = (const float*)d_in[6];
    const float* W2   = (const float*)d_in[7];
    const float* b2   = (const float*)d_in[8];
    const float* g1   = (const float*)d_in[9];
    const float* be1  = (const float*)d_in[10];
    const float* g2   = (const float*)d_in[11];
    const float* be2  = (const float*)d_in[12];
    float* out = (float*)d_out;

    char* ws = (char*)d_ws;
    u16* Xbf   = (u16*)(ws + 0);
    u16* WqkvT = (u16*)(ws + 8388608);
    u16* WoT   = (u16*)(ws + 14680064);
    u16* QK    = (u16*)(ws + 16777216);        // 4096 x 2048
    u16* VT    = (u16*)(ws + 33554432);        // [2*16][64][2048]
    u16* AO    = (u16*)(ws + 41943040);
    u16* S1    = (u16*)(ws + 16777216);
    u16* H1    = (u16*)(ws + 0);
    u16* Gbuf  = (u16*)(ws + 8388608);
    u16* S2    = (u16*)(ws + 41943040);
    u16* W1T   = (u16*)d_out;
    u16* W2T   = (u16*)d_out + 4194304;

    cvt_bf16<<<4096, 256, 0, stream>>>(X, Xbf);
    cvt_transpose<<<dim3(16, 48), 256, 0, stream>>>(Wqkv, WqkvT, 1024, 3072);
    cvt_transpose<<<dim3(16, 16), 256, 0, stream>>>(Wo,   WoT,   1024, 1024);
    cvt_transpose<<<dim3(16, 64), 256, 0, stream>>>(W1,   W1T,   1024, 4096);
    cvt_transpose<<<dim3(64, 16), 256, 0, stream>>>(W2,   W2T,   4096, 1024);

    gemm_bt<3,128,0><<<dim3(32, 24), 256, 0, stream>>>(Xbf, WqkvT, bqkv, nullptr, QK, VT, 4096, 3072, 1024);
    attn_kernel<<<dim3(16, 16, 2), 512, 0, stream>>>(QK, VT, AO);
    gemm_bt<1,128,1><<<dim3(32, 8), 256, 0, stream>>>(AO, WoT, bo, Xbf, S1, nullptr, 4096, 1024, 1024);
    ln_kernel<0><<<4096, 256, 0, stream>>>(S1, g1, be1, H1);
    gemm_bt<2,128,0><<<dim3(32, 32), 256, 0, stream>>>(H1, W1T, b1, nullptr, Gbuf, nullptr, 4096, 4096, 1024);
    gemm_bt<1,128,1><<<dim3(32, 8), 256, 0, stream>>>(Gbuf, W2T, b2, H1, S2, nullptr, 4096, 1024, 4096);
    ln_kernel<1><<<4096, 256, 0, stream>>>(S2, g2, be2, out);
}

// Round 8
// 359.141 us; speedup vs baseline: 1.0175x; 1.0175x over previous
//
#include <hip/hip_runtime.h>
#include <cmath>

typedef unsigned short u16;
typedef __bf16 bf16x8 __attribute__((ext_vector_type(8)));
typedef float f32x4 __attribute__((ext_vector_type(4)));

#define DEVI __device__ __forceinline__

DEVI float b2f(u16 u){ union{unsigned int i; float f;} v; v.i=(unsigned int)u<<16; return v.f; }
DEVI u16 f2b(float f){ union{unsigned int i; float f;} v; v.f=f;
    unsigned int r=(v.i+0x7FFFu+((v.i>>16)&1u))>>16; return (u16)r; }

DEVI void gload_lds16(const u16* g, u16* l){
    __builtin_amdgcn_global_load_lds((__attribute__((address_space(1))) void*)g,
                                     (__attribute__((address_space(3))) void*)l,
                                     16, 0, 0);
}

// ---------------------------------------------------------------------------
// fp32 -> bf16 elementwise (X ingest). 4 elems/thread.
// ---------------------------------------------------------------------------
__global__ __launch_bounds__(256)
void cvt_bf16(const float* __restrict__ in, u16* __restrict__ out)
{
    const int i = (blockIdx.x * 256 + threadIdx.x) * 4;
    float4 v = *(const float4*)&in[i];
    ushort4 o;
    o.x = f2b(v.x); o.y = f2b(v.y); o.z = f2b(v.z); o.w = f2b(v.w);
    *(ushort4*)&out[i] = o;
}

// ---------------------------------------------------------------------------
// fp32 [R,C] -> bf16 [C,R] transpose (weight ingest). 64x64 LDS tiles.
// ---------------------------------------------------------------------------
__global__ __launch_bounds__(256)
void cvt_transpose(const float* __restrict__ in, u16* __restrict__ out, int R, int C)
{
    __shared__ __align__(16) u16 tile[64*72];
    const int rb = blockIdx.x*64, cb = blockIdx.y*64;
    const int t = threadIdx.x;
    const int r = t >> 3, c0 = (t & 7) * 8;
    #pragma unroll
    for (int rr = 0; rr < 2; rr++) {
        const int row = r + rr*32;
        float4 a = *(const float4*)&in[(long)(rb + row)*C + cb + c0];
        float4 b = *(const float4*)&in[(long)(rb + row)*C + cb + c0 + 4];
        u16* tp = &tile[row*72 + c0];
        tp[0]=f2b(a.x); tp[1]=f2b(a.y); tp[2]=f2b(a.z); tp[3]=f2b(a.w);
        tp[4]=f2b(b.x); tp[5]=f2b(b.y); tp[6]=f2b(b.z); tp[7]=f2b(b.w);
    }
    __syncthreads();
    #pragma unroll
    for (int rr = 0; rr < 2; rr++) {
        const int cr = r + rr*32;
        u16 tmp[8];
        #pragma unroll
        for (int j = 0; j < 8; j++) tmp[j] = tile[(c0 + j)*72 + cr];
        *(uint4*)&out[(long)(cb + cr)*R + rb + c0] = *(uint4*)tmp;
    }
}

// ---------------------------------------------------------------------------
// GEMM: C[M,N] = A[M,K] @ Bt[N,K]^T + bias. bf16 in/out, fp32 accum.
// Tile BM x 128, BK=64 (two 32-wide panels). 4 waves.
// QUAD-XOR LDS swizzle (both-sides, rule #21): staging quads contiguous
// (VMEM coalescing preserved); fragment read covers all 8 bank-groups per
// octet -> zero LDS conflicts (verified r6: SQ_LDS_BANK_CONFLICT = 0).
// PIPE=0: two-barrier serial staging (for kernels at 3-4 blocks/CU where
//         implicit wave overlap hides latency).
// PIPE=2: 3-stage counted-vmcnt pipeline (T3/T4). For the N=1024 GEMMs at
//         1 block/CU (4 waves): triple-buffer LDS; s_waitcnt vmcnt(8) keeps
//         the NEXT stage's loads in flight ACROSS the barrier (never drain
//         to 0); stage t+2 issued right after the barrier. Loads consumed
//         2 iterations after issue -> HBM latency off the critical path.
//         (r7 lesson: BM=128 DBUF at 1 blk/CU = 73.9us, ~1300 exposed
//         cyc/step from the barrier's implicit vmcnt(0) drain.)
// Race audit: buffer (t+2)%3 == (t-1)%3 was last read in iter t-1, and all
// waves finished that compute before arriving at iter t's barrier; per-wave
// vmcnt + barrier makes all stage-t writes visible before compute of t.
// EPI: 0 = bias, 1 = bias+residual, 2 = bias+tanh-GELU,
//      3 = QKV split: cols<2048 -> C row-major (width 2048),
//          cols>=2048 (V) -> C2 = VT[b*16+h][d][tok] transposed.
// ---------------------------------------------------------------------------
template<int EPI, int BM, int PIPE>
__global__ __launch_bounds__(256)
void gemm_bt(const u16* __restrict__ A, const u16* __restrict__ Bt,
             const float* __restrict__ bias, const u16* __restrict__ Res,
             u16* __restrict__ C, u16* __restrict__ C2, int M, int N, int K)
{
    constexpr int RM = BM / 32;
    constexpr int NA = (BM / 16) * 2 / 4;
    constexpr int ASZ = BM*64, BSZ = 128*64;
    constexpr int NBUF = (PIPE == 2) ? 3 : 1;
    __shared__ __align__(16) u16 As[NBUF*ASZ];
    __shared__ __align__(16) u16 Bs[NBUF*BSZ];
    const int tid  = threadIdx.x;
    const int wave = tid >> 6, lane = tid & 63;
    const int tm = blockIdx.x * BM, tn = blockIdx.y * 128;

    // staging: lane quad a fetches row a's 64B, 16B-chunks XOR-permuted
    const int rs = lane >> 2, cs = ((lane & 3) ^ ((lane >> 3) & 3)) * 8;
    const u16* gA[NA]; u16* lA[NA];
    #pragma unroll
    for (int i = 0; i < NA; i++) {
        const int c = wave + i*4;
        const int p = c / (BM/16), rb = c % (BM/16);
        gA[i] = A + (long)(tm + rb*16 + rs)*K + p*32 + cs;
        lA[i] = As + p*(BM*32) + rb*512;
    }
    const u16* gB[4]; u16* lB[4];
    #pragma unroll
    for (int i = 0; i < 4; i++) {
        const int c = wave + i*4;
        const int p = c >> 3, rb = c & 7;
        gB[i] = Bt + (long)(tn + rb*16 + rs)*K + p*32 + cs;
        lB[i] = Bs + p*(128*32) + rb*512;
    }

    const int wm = (wave >> 1) * (BM/2), wn = (wave & 1) * 64;
    const int fr = lane & 15, fq = lane >> 4;
    const int fs = (fq ^ ((fr >> 1) & 3)) * 8;   // swizzled 16B-slot within row

    f32x4 acc[RM][4] = {};

    if constexpr (PIPE == 2) {
        static_assert(NA + 4 == 8, "vmcnt immediates assume 8 loads/thread/stage");
        const int nk = K >> 6;
        // prologue: stages 0 and 1
        #pragma unroll
        for (int i = 0; i < NA; i++) gload_lds16(gA[i], lA[i]);
        #pragma unroll
        for (int i = 0; i < 4; i++)  gload_lds16(gB[i], lB[i]);
        #pragma unroll
        for (int i = 0; i < NA; i++) gload_lds16(gA[i] + 64, lA[i] + ASZ);
        #pragma unroll
        for (int i = 0; i < 4; i++)  gload_lds16(gB[i] + 64, lB[i] + BSZ);
        int bc = 0;                       // buffer holding stage t
        for (int t = 0; t < nk; t++) {
            if (t + 1 < nk) asm volatile("s_waitcnt vmcnt(8)" ::: "memory");
            else            asm volatile("s_waitcnt vmcnt(0)" ::: "memory");
            __builtin_amdgcn_s_barrier();
            __builtin_amdgcn_sched_barrier(0);
            if (t + 2 < nk) {             // issue stage t+2 into (t+2)%3
                int bn = bc + 2; if (bn >= 3) bn -= 3;
                const int k0 = (t + 2) << 6;
                #pragma unroll
                for (int i = 0; i < NA; i++) gload_lds16(gA[i] + k0, lA[i] + bn*ASZ);
                #pragma unroll
                for (int i = 0; i < 4; i++)  gload_lds16(gB[i] + k0, lB[i] + bn*BSZ);
            }
            const u16* Ab = As + bc*ASZ;
            const u16* Bb = Bs + bc*BSZ;
            #pragma unroll
            for (int p = 0; p < 2; p++) {
                bf16x8 af[RM], bfr[4];
                #pragma unroll
                for (int i = 0; i < RM; i++)
                    af[i]  = *(const bf16x8*)&Ab[p*(BM*32) + (wm + i*16 + fr)*32 + fs];
                #pragma unroll
                for (int j = 0; j < 4; j++)
                    bfr[j] = *(const bf16x8*)&Bb[p*(128*32) + (wn + j*16 + fr)*32 + fs];
                #pragma unroll
                for (int i = 0; i < RM; i++)
                    #pragma unroll
                    for (int j = 0; j < 4; j++)
                        acc[i][j] = __builtin_amdgcn_mfma_f32_16x16x32_bf16(af[i], bfr[j], acc[i][j], 0, 0, 0);
            }
            bc++; if (bc >= 3) bc = 0;
        }
    } else {
        for (int k0 = 0; k0 < K; k0 += 64) {
            __syncthreads();
            #pragma unroll
            for (int i = 0; i < NA; i++) gload_lds16(gA[i] + k0, lA[i]);
            #pragma unroll
            for (int i = 0; i < 4; i++)  gload_lds16(gB[i] + k0, lB[i]);
            __syncthreads();
            #pragma unroll
            for (int p = 0; p < 2; p++) {
                bf16x8 af[RM], bfr[4];
                #pragma unroll
                for (int i = 0; i < RM; i++)
                    af[i]  = *(const bf16x8*)&As[p*(BM*32) + (wm + i*16 + fr)*32 + fs];
                #pragma unroll
                for (int j = 0; j < 4; j++)
                    bfr[j] = *(const bf16x8*)&Bs[p*(128*32) + (wn + j*16 + fr)*32 + fs];
                #pragma unroll
                for (int i = 0; i < RM; i++)
                    #pragma unroll
                    for (int j = 0; j < 4; j++)
                        acc[i][j] = __builtin_amdgcn_mfma_f32_16x16x32_bf16(af[i], bfr[j], acc[i][j], 0, 0, 0);
            }
        }
    }

    #pragma unroll
    for (int i = 0; i < RM; i++) {
        const int row = tm + wm + i*16 + fq*4;
        #pragma unroll
        for (int j = 0; j < 4; j++) {
            const int col = tn + wn + j*16 + fr;
            const float bv = bias[col];
            if (EPI == 3 && col >= 2048) {
                const int hh = (col - 2048) >> 6, dd = (col - 2048) & 63;
                const int batch = row >> 11, tok = row & 2047;
                u16 pk[4];
                #pragma unroll
                for (int r = 0; r < 4; r++) pk[r] = f2b(acc[i][j][r] + bv);
                *(uint2*)&C2[((long)(batch*16 + hh)*64 + dd)*2048 + tok] = *(uint2*)pk;
            } else {
                const int cw = (EPI == 3) ? 2048 : N;
                #pragma unroll
                for (int r = 0; r < 4; r++) {
                    float v = acc[i][j][r] + bv;
                    const long idx = (long)(row + r)*cw + col;
                    if (EPI == 1) v += b2f(Res[idx]);
                    if (EPI == 2) {
                        const float u = v + 0.044715f*v*v*v;
                        const float t = exp2f(u * 2.302208f);
                        v = v * t * __builtin_amdgcn_rcpf(t + 1.f);
                    }
                    C[idx] = f2b(v);
                }
            }
        }
    }
}

// ---------------------------------------------------------------------------
// Flash attention v9, causal. PAIRED q-tiles + SPLIT-KEY wave groups +
// quad-XOR K/V LDS swizzle (same both-sides trick as the GEMM).
// Block = 512 threads = 2 groups x 4 waves; (pair, head, batch) grid 16x16x2.
// ---------------------------------------------------------------------------
__global__ __launch_bounds__(512)
void attn_kernel(const u16* __restrict__ QK, const u16* __restrict__ VT,
                 u16* __restrict__ O)
{
    constexpr float CS = 0.18033688011112042f;   // 0.125 * log2(e)
    __shared__ __align__(16) u16 smem[40960];

    const int tid = threadIdx.x, wave = tid >> 6, lane = tid & 63;
    const int grp = wave >> 2, wg = wave & 3;
    const int pair = blockIdx.x, h = blockIdx.y, b = blockIdx.z;
    const int fr = lane & 15, fq = lane >> 4;
    const long qkbase = (long)b*2048*2048;
    const long vtbase = (long)(b*16 + h)*64*2048;
    const int rs = lane >> 2, cs2 = ((lane & 3) ^ ((lane >> 3) & 3)) * 8;
    const int fs = (fq ^ ((fr >> 1) & 3)) * 8;
    const int sw = (fr & 7) * 8;
    const int KsBase = grp*8192;
    const int VsBase = 16384 + grp*8192;
    u16* pw = &smem[32768 + wave*1024];

    #define ISSUE(bf, k0)                                                      \
        _Pragma("unroll")                                                      \
        for (int i = 0; i < 2; i++) {                                          \
            const int c = wg + i*4;                                            \
            const int kp = c >> 2, krb = c & 3;                                \
            gload_lds16(QK + qkbase + (long)((k0) + krb*16 + rs)*2048          \
                           + 1024 + h*64 + kp*32 + cs2,                        \
                        &smem[KsBase + (bf)*4096 + kp*2048 + krb*512]);        \
            const int vp = c & 1, vrb = c >> 1;                                \
            gload_lds16(VT + vtbase + (long)(vrb*16 + rs)*2048                 \
                           + (k0) + vp*32 + cs2,                               \
                        &smem[VsBase + (bf)*4096 + vp*2048 + vrb*512]);        \
        }

    #pragma unroll 1
    for (int which = 0; which < 2; which++) {
        const int qt = which ? pair : (31 - pair);

        bf16x8 bq[2];
        #pragma unroll
        for (int ks = 0; ks < 2; ks++)
            bq[ks] = *(const bf16x8*)&QK[qkbase + (long)(qt*64 + wg*16 + fr)*2048
                                         + h*64 + ks*32 + fq*8];

        const int q_glob = qt*64 + wg*16 + fr;
        const int q_wmin = qt*64 + wg*16;
        f32x4 o[4] = {};
        float m_i = -1e30f, l_i = 0.f;
        const int nkt = qt + 1;
        const int nit = (nkt + 1) >> 1;
        const int myn = (nkt + 1 - grp) >> 1;

        if (which) __syncthreads();
        if (grp < nkt) { ISSUE(0, grp*64) }

        for (int it = 0; it < nit; it++) {
            const int kt = 2*it + grp;
            const int k0 = kt * 64;
            const int cur = it & 1;
            __syncthreads();
            if (kt + 2 < nkt) { ISSUE(cur ^ 1, k0 + 128) }

            if (it < myn) {
                f32x4 st[4];
                #pragma unroll
                for (int mt = 0; mt < 4; mt++) st[mt] = (f32x4){0.f,0.f,0.f,0.f};
                #pragma unroll
                for (int mt = 0; mt < 4; mt++)
                    #pragma unroll
                    for (int ks = 0; ks < 2; ks++) {
                        bf16x8 ak = *(const bf16x8*)&smem[KsBase + cur*4096 + ks*2048 + (mt*16 + fr)*32 + fs];
                        st[mt] = __builtin_amdgcn_mfma_f32_16x16x32_bf16(ak, bq[ks], st[mt], 0, 0, 0);
                    }

                float mx = -1e30f;
                if (k0 + 63 > q_wmin) {
                    #pragma unroll
                    for (int mt = 0; mt < 4; mt++)
                        #pragma unroll
                        for (int r = 0; r < 4; r++) {
                            const int key = k0 + mt*16 + fq*4 + r;
                            float v = st[mt][r];
                            if (key > q_glob) v = -1e30f;
                            st[mt][r] = v;
                            mx = fmaxf(mx, v);
                        }
                } else {
                    #pragma unroll
                    for (int mt = 0; mt < 4; mt++)
                        #pragma unroll
                        for (int r = 0; r < 4; r++) mx = fmaxf(mx, st[mt][r]);
                }
                mx = fmaxf(mx, __shfl_xor(mx, 16, 64));
                mx = fmaxf(mx, __shfl_xor(mx, 32, 64));

                if (mx > m_i + 44.357f) {
                    const float alpha = exp2f((m_i - mx) * CS);
                    #pragma unroll
                    for (int dt = 0; dt < 4; dt++)
                        #pragma unroll
                        for (int r = 0; r < 4; r++) o[dt][r] *= alpha;
                    l_i *= alpha;
                    m_i = mx;
                }
                const float nms = -m_i * CS;
                float ps = 0.f;
                #pragma unroll
                for (int mt = 0; mt < 4; mt++)
                    #pragma unroll
                    for (int r = 0; r < 4; r++) {
                        const float p = exp2f(fmaf(st[mt][r], CS, nms));
                        st[mt][r] = p; ps += p;
                    }
                ps += __shfl_xor(ps, 16, 64);
                ps += __shfl_xor(ps, 32, 64);
                l_i += ps;

                #pragma unroll
                for (int mt = 0; mt < 4; mt++)
                    #pragma unroll
                    for (int d = 0; d < 2; d++) {
                        unsigned pk;
                        asm("v_cvt_pk_bf16_f32 %0, %1, %2"
                            : "=v"(pk) : "v"(st[mt][2*d]), "v"(st[mt][2*d+1]));
                        *(unsigned*)&pw[fr*64 + ((mt*16 + fq*4 + 2*d) ^ sw)] = pk;
                    }
                __asm__ volatile("" ::: "memory");
                bf16x8 bp[2];
                #pragma unroll
                for (int kk = 0; kk < 2; kk++)
                    bp[kk] = *(const bf16x8*)&pw[fr*64 + ((kk*32 + fq*8) ^ sw)];
                #pragma unroll
                for (int dt = 0; dt < 4; dt++)
                    #pragma unroll
                    for (int kk = 0; kk < 2; kk++) {
                        bf16x8 av = *(const bf16x8*)&smem[VsBase + cur*4096 + kk*2048 + (dt*16 + fr)*32 + fs];
                        o[dt] = __builtin_amdgcn_mfma_f32_16x16x32_bf16(av, bp[kk], o[dt], 0, 0, 0);
                    }
                __asm__ volatile("" ::: "memory");
            }
        }

        __syncthreads();
        float* MB = (float*)&smem[8192];
        float* ML = (float*)&smem[24576];
        if (grp == 1) {
            #pragma unroll
            for (int dt = 0; dt < 4; dt++)
                *(f32x4*)&MB[(wg*64 + lane)*16 + dt*4] = o[dt];
            if (fq == 0) {
                ML[(wg*16 + fr)*2]     = m_i;
                ML[(wg*16 + fr)*2 + 1] = l_i;
            }
        }
        __syncthreads();
        if (grp == 0) {
            const float m1 = ML[(wg*16 + fr)*2];
            const float l1 = ML[(wg*16 + fr)*2 + 1];
            const float m  = fmaxf(m_i, m1);
            const float e0 = exp2f((m_i - m) * CS);
            const float e1 = exp2f((m1  - m) * CS);
            const float rl = __builtin_amdgcn_rcpf(l_i*e0 + l1*e1);
            const long orow = (long)b*2048 + qt*64 + wg*16 + fr;
            #pragma unroll
            for (int dt = 0; dt < 4; dt++) {
                f32x4 o1 = *(const f32x4*)&MB[(wg*64 + lane)*16 + dt*4];
                u16 pk[4];
                #pragma unroll
                for (int r = 0; r < 4; r++)
                    pk[r] = f2b((o[dt][r]*e0 + o1[r]*e1) * rl);
                *(uint2*)&O[orow*1024 + h*64 + dt*16 + fq*4] = *(uint2*)pk;
            }
        }
    }
    #undef ISSUE
}

// ---------------------------------------------------------------------------
// LayerNorm over 1024 cols; bf16 in, fp32 gamma/beta; OUTF32 selects output.
// ---------------------------------------------------------------------------
template<int OUTF32>
__global__ __launch_bounds__(256)
void ln_kernel(const u16* __restrict__ X, const float* __restrict__ G,
               const float* __restrict__ B, void* __restrict__ Yv)
{
    __shared__ float red[8];
    const int tid = threadIdx.x;
    const long row = blockIdx.x;
    const u16* x = X + row*1024;
    ushort4 u = *(const ushort4*)&x[tid*4];
    const float v0 = b2f(u.x), v1 = b2f(u.y), v2 = b2f(u.z), v3 = b2f(u.w);
    float s = v0+v1+v2+v3;
    float q = v0*v0+v1*v1+v2*v2+v3*v3;
    #pragma unroll
    for (int off = 32; off >= 1; off >>= 1) {
        s += __shfl_xor(s, off, 64);
        q += __shfl_xor(q, off, 64);
    }
    const int wv = tid >> 6;
    if ((tid & 63) == 0) { red[wv*2] = s; red[wv*2+1] = q; }
    __syncthreads();
    s = red[0]+red[2]+red[4]+red[6];
    q = red[1]+red[3]+red[5]+red[7];
    const float mu = s * (1.f/1024.f);
    const float rstd = rsqrtf(fmaxf(q*(1.f/1024.f) - mu*mu, 0.f) + 1e-5f);
    float4 g4 = *(const float4*)&G[tid*4];
    float4 b4 = *(const float4*)&B[tid*4];
    const float y0 = (v0-mu)*rstd*g4.x + b4.x;
    const float y1 = (v1-mu)*rstd*g4.y + b4.y;
    const float y2 = (v2-mu)*rstd*g4.z + b4.z;
    const float y3 = (v3-mu)*rstd*g4.w + b4.w;
    if (OUTF32) {
        float4 o = make_float4(y0, y1, y2, y3);
        *(float4*)&((float*)Yv)[row*1024 + tid*4] = o;
    } else {
        ushort4 o;
        o.x = f2b(y0); o.y = f2b(y1); o.z = f2b(y2); o.w = f2b(y3);
        *(ushort4*)&((u16*)Yv)[row*1024 + tid*4] = o;
    }
}

// ---------------------------------------------------------------------------
// Workspace (48 MiB of d_ws + d_out as W1T/W2T scratch), liveness-audited:
//   Xbf [0,8) | WqkvT [8,14) | WoT [14,16) | QK [16,32) | VT [32,40) |
//   AO [40,48) | S1 [16,24) after attn | H1 [0,8) after LN1 |
//   Gbuf [8,40) FF1..FF2 | S2 [40,48) | W1T/W2T in d_out (dead before LN2)
// ---------------------------------------------------------------------------
extern "C" void kernel_launch(void* const* d_in, const int* in_sizes, int n_in,
                              void* d_out, int out_size, void* d_ws, size_t ws_size,
                              hipStream_t stream)
{
    const float* X    = (const float*)d_in[0];
    const float* Wqkv = (const float*)d_in[1];
    const float* bqkv = (const float*)d_in[2];
    const float* Wo   = (const float*)d_in[3];
    const float* bo   = (const float*)d_in[4];
    const float* W1   = (const float*)d_in[5];
    const float* b1   = (const float*)d_in[6];
    const float* W2   = (const float*)d_in[7];
    const float* b2   = (const float*)d_in[8];
    const float* g1   = (const float*)d_in[9];
    const float* be1  = (const float*)d_in[10];
    const float* g2   = (const float*)d_in[11];
    const float* be2  = (const float*)d_in[12];
    float* out = (float*)d_out;

    char* ws = (char*)d_ws;
    u16* Xbf   = (u16*)(ws + 0);
    u16* WqkvT = (u16*)(ws + 8388608);
    u16* WoT   = (u16*)(ws + 14680064);
    u16* QK    = (u16*)(ws + 16777216);        // 4096 x 2048
    u16* VT    = (u16*)(ws + 33554432);        // [2*16][64][2048]
    u16* AO    = (u16*)(ws + 41943040);
    u16* S1    = (u16*)(ws + 16777216);
    u16* H1    = (u16*)(ws + 0);
    u16* Gbuf  = (u16*)(ws + 8388608);
    u16* S2    = (u16*)(ws + 41943040);
    u16* W1T   = (u16*)d_out;
    u16* W2T   = (u16*)d_out + 4194304;

    cvt_bf16<<<4096, 256, 0, stream>>>(X, Xbf);
    cvt_transpose<<<dim3(16, 48), 256, 0, stream>>>(Wqkv, WqkvT, 1024, 3072);
    cvt_transpose<<<dim3(16, 16), 256, 0, stream>>>(Wo,   WoT,   1024, 1024);
    cvt_transpose<<<dim3(16, 64), 256, 0, stream>>>(W1,   W1T,   1024, 4096);
    cvt_transpose<<<dim3(64, 16), 256, 0, stream>>>(W2,   W2T,   4096, 1024);

    gemm_bt<3,128,0><<<dim3(32, 24), 256, 0, stream>>>(Xbf, WqkvT, bqkv, nullptr, QK, VT, 4096, 3072, 1024);
    attn_kernel<<<dim3(16, 16, 2), 512, 0, stream>>>(QK, VT, AO);
    gemm_bt<1,128,2><<<dim3(32, 8), 256, 0, stream>>>(AO, WoT, bo, Xbf, S1, nullptr, 4096, 1024, 1024);
    ln_kernel<0><<<4096, 256, 0, stream>>>(S1, g1, be1, H1);
    gemm_bt<2,128,0><<<dim3(32, 32), 256, 0, stream>>>(H1, W1T, b1, nullptr, Gbuf, nullptr, 4096, 4096, 1024);
    gemm_bt<1,128,2><<<dim3(32, 8), 256, 0, stream>>>(Gbuf, W2T, b2, H1, S2, nullptr, 4096, 1024, 4096);
    ln_kernel<1><<<4096, 256, 0, stream>>>(S2, g2, be2, out);
}

// Round 9
// 348.173 us; speedup vs baseline: 1.0495x; 1.0315x over previous
//
#include <hip/hip_runtime.h>
#include <cmath>

typedef unsigned short u16;
typedef __bf16 bf16x8 __attribute__((ext_vector_type(8)));
typedef float f32x4 __attribute__((ext_vector_type(4)));

#define DEVI __device__ __forceinline__

DEVI float b2f(u16 u){ union{unsigned int i; float f;} v; v.i=(unsigned int)u<<16; return v.f; }
DEVI u16 f2b(float f){ union{unsigned int i; float f;} v; v.f=f;
    unsigned int r=(v.i+0x7FFFu+((v.i>>16)&1u))>>16; return (u16)r; }

DEVI void gload_lds16(const u16* g, u16* l){
    __builtin_amdgcn_global_load_lds((__attribute__((address_space(1))) void*)g,
                                     (__attribute__((address_space(3))) void*)l,
                                     16, 0, 0);
}

// ---------------------------------------------------------------------------
// fp32 -> bf16 elementwise (X ingest). 4 elems/thread.
// ---------------------------------------------------------------------------
__global__ __launch_bounds__(256)
void cvt_bf16(const float* __restrict__ in, u16* __restrict__ out)
{
    const int i = (blockIdx.x * 256 + threadIdx.x) * 4;
    float4 v = *(const float4*)&in[i];
    ushort4 o;
    o.x = f2b(v.x); o.y = f2b(v.y); o.z = f2b(v.z); o.w = f2b(v.w);
    *(ushort4*)&out[i] = o;
}

// ---------------------------------------------------------------------------
// fp32 [R,C] -> bf16 [C,R] transpose (weight ingest). 64x64 LDS tiles.
// ---------------------------------------------------------------------------
__global__ __launch_bounds__(256)
void cvt_transpose(const float* __restrict__ in, u16* __restrict__ out, int R, int C)
{
    __shared__ __align__(16) u16 tile[64*72];
    const int rb = blockIdx.x*64, cb = blockIdx.y*64;
    const int t = threadIdx.x;
    const int r = t >> 3, c0 = (t & 7) * 8;
    #pragma unroll
    for (int rr = 0; rr < 2; rr++) {
        const int row = r + rr*32;
        float4 a = *(const float4*)&in[(long)(rb + row)*C + cb + c0];
        float4 b = *(const float4*)&in[(long)(rb + row)*C + cb + c0 + 4];
        u16* tp = &tile[row*72 + c0];
        tp[0]=f2b(a.x); tp[1]=f2b(a.y); tp[2]=f2b(a.z); tp[3]=f2b(a.w);
        tp[4]=f2b(b.x); tp[5]=f2b(b.y); tp[6]=f2b(b.z); tp[7]=f2b(b.w);
    }
    __syncthreads();
    #pragma unroll
    for (int rr = 0; rr < 2; rr++) {
        const int cr = r + rr*32;
        u16 tmp[8];
        #pragma unroll
        for (int j = 0; j < 8; j++) tmp[j] = tile[(c0 + j)*72 + cr];
        *(uint4*)&out[(long)(cb + cr)*R + rb + c0] = *(uint4*)tmp;
    }
}

// ---------------------------------------------------------------------------
// GEMM: C[M,N] = A[M,K] @ Bt[N,K]^T + bias. bf16 in/out, fp32 accum.
// Tile BM x 128, BK=64 (two 32-wide panels). 4 waves.
// QUAD-XOR LDS swizzle (both-sides, rule #21): staging quads contiguous
// (VMEM coalescing preserved); fragment read covers all 8 bank-groups per
// octet -> zero LDS conflicts (verified r6: SQ_LDS_BANK_CONFLICT = 0).
// PIPE=0: two-barrier serial staging (kernels at 3-4 blocks/CU, implicit
//         wave overlap hides latency).
// PIPE=2: 3-stage counted-vmcnt pipeline (T3/T4): triple-buffer LDS;
//         s_waitcnt vmcnt(NLD) retires only stage t, keeping stages
//         t+1/t+2 in flight ACROSS the raw s_barrier; stage t+2 issued
//         right after. Correct because EVERY wave waits on its own stage-t
//         loads before the barrier -> all stage-t LDS writes visible.
// r7/r8 lesson: BM=128 at 1 blk/CU (1 wave/SIMD) is latency-chain-bound
// regardless of pipeline depth (DBUF 73.9us == counted-vmcnt 73.1us;
// no TLP to hide ds_read->MFMA deps). Wave residency >=2/SIMD is a hard
// prerequisite -> N=1024 GEMMs use BM=64 (2 blk/CU, 16 waves/CU) + PIPE=2
// (removes DBUF's ~450cyc/step residual drain measured at r6's 58.9us).
// EPI: 0 = bias, 1 = bias+residual, 2 = bias+tanh-GELU,
//      3 = QKV split: cols<2048 -> C row-major (width 2048),
//          cols>=2048 (V) -> C2 = VT[b*16+h][d][tok] transposed.
// ---------------------------------------------------------------------------
template<int EPI, int BM, int PIPE>
__global__ __launch_bounds__(256)
void gemm_bt(const u16* __restrict__ A, const u16* __restrict__ Bt,
             const float* __restrict__ bias, const u16* __restrict__ Res,
             u16* __restrict__ C, u16* __restrict__ C2, int M, int N, int K)
{
    constexpr int RM = BM / 32;
    constexpr int NA = (BM / 16) * 2 / 4;
    constexpr int ASZ = BM*64, BSZ = 128*64;
    constexpr int NBUF = (PIPE == 2) ? 3 : 1;
    __shared__ __align__(16) u16 As[NBUF*ASZ];
    __shared__ __align__(16) u16 Bs[NBUF*BSZ];
    const int tid  = threadIdx.x;
    const int wave = tid >> 6, lane = tid & 63;
    const int tm = blockIdx.x * BM, tn = blockIdx.y * 128;

    // staging: lane quad a fetches row a's 64B, 16B-chunks XOR-permuted
    const int rs = lane >> 2, cs = ((lane & 3) ^ ((lane >> 3) & 3)) * 8;
    const u16* gA[NA]; u16* lA[NA];
    #pragma unroll
    for (int i = 0; i < NA; i++) {
        const int c = wave + i*4;
        const int p = c / (BM/16), rb = c % (BM/16);
        gA[i] = A + (long)(tm + rb*16 + rs)*K + p*32 + cs;
        lA[i] = As + p*(BM*32) + rb*512;
    }
    const u16* gB[4]; u16* lB[4];
    #pragma unroll
    for (int i = 0; i < 4; i++) {
        const int c = wave + i*4;
        const int p = c >> 3, rb = c & 7;
        gB[i] = Bt + (long)(tn + rb*16 + rs)*K + p*32 + cs;
        lB[i] = Bs + p*(128*32) + rb*512;
    }

    const int wm = (wave >> 1) * (BM/2), wn = (wave & 1) * 64;
    const int fr = lane & 15, fq = lane >> 4;
    const int fs = (fq ^ ((fr >> 1) & 3)) * 8;   // swizzled 16B-slot within row

    f32x4 acc[RM][4] = {};

    if constexpr (PIPE == 2) {
        constexpr int NLD = NA + 4;   // loads/thread/stage (6 @BM=64, 8 @BM=128)
        static_assert(NLD == 6 || NLD == 8, "vmcnt literal dispatch");
        const int nk = K >> 6;
        // prologue: stages 0 and 1
        #pragma unroll
        for (int i = 0; i < NA; i++) gload_lds16(gA[i], lA[i]);
        #pragma unroll
        for (int i = 0; i < 4; i++)  gload_lds16(gB[i], lB[i]);
        #pragma unroll
        for (int i = 0; i < NA; i++) gload_lds16(gA[i] + 64, lA[i] + ASZ);
        #pragma unroll
        for (int i = 0; i < 4; i++)  gload_lds16(gB[i] + 64, lB[i] + BSZ);
        int bc = 0;                       // buffer holding stage t
        for (int t = 0; t < nk; t++) {
            if (t + 1 < nk) {
                if constexpr (NLD == 8) asm volatile("s_waitcnt vmcnt(8)" ::: "memory");
                else                    asm volatile("s_waitcnt vmcnt(6)" ::: "memory");
            } else {
                asm volatile("s_waitcnt vmcnt(0)" ::: "memory");
            }
            __builtin_amdgcn_s_barrier();
            __builtin_amdgcn_sched_barrier(0);
            if (t + 2 < nk) {             // issue stage t+2 into (t+2)%3
                int bn = bc + 2; if (bn >= 3) bn -= 3;
                const int k0 = (t + 2) << 6;
                #pragma unroll
                for (int i = 0; i < NA; i++) gload_lds16(gA[i] + k0, lA[i] + bn*ASZ);
                #pragma unroll
                for (int i = 0; i < 4; i++)  gload_lds16(gB[i] + k0, lB[i] + bn*BSZ);
            }
            const u16* Ab = As + bc*ASZ;
            const u16* Bb = Bs + bc*BSZ;
            #pragma unroll
            for (int p = 0; p < 2; p++) {
                bf16x8 af[RM], bfr[4];
                #pragma unroll
                for (int i = 0; i < RM; i++)
                    af[i]  = *(const bf16x8*)&Ab[p*(BM*32) + (wm + i*16 + fr)*32 + fs];
                #pragma unroll
                for (int j = 0; j < 4; j++)
                    bfr[j] = *(const bf16x8*)&Bb[p*(128*32) + (wn + j*16 + fr)*32 + fs];
                #pragma unroll
                for (int i = 0; i < RM; i++)
                    #pragma unroll
                    for (int j = 0; j < 4; j++)
                        acc[i][j] = __builtin_amdgcn_mfma_f32_16x16x32_bf16(af[i], bfr[j], acc[i][j], 0, 0, 0);
            }
            bc++; if (bc >= 3) bc = 0;
        }
    } else {
        for (int k0 = 0; k0 < K; k0 += 64) {
            __syncthreads();
            #pragma unroll
            for (int i = 0; i < NA; i++) gload_lds16(gA[i] + k0, lA[i]);
            #pragma unroll
            for (int i = 0; i < 4; i++)  gload_lds16(gB[i] + k0, lB[i]);
            __syncthreads();
            #pragma unroll
            for (int p = 0; p < 2; p++) {
                bf16x8 af[RM], bfr[4];
                #pragma unroll
                for (int i = 0; i < RM; i++)
                    af[i]  = *(const bf16x8*)&As[p*(BM*32) + (wm + i*16 + fr)*32 + fs];
                #pragma unroll
                for (int j = 0; j < 4; j++)
                    bfr[j] = *(const bf16x8*)&Bs[p*(128*32) + (wn + j*16 + fr)*32 + fs];
                #pragma unroll
                for (int i = 0; i < RM; i++)
                    #pragma unroll
                    for (int j = 0; j < 4; j++)
                        acc[i][j] = __builtin_amdgcn_mfma_f32_16x16x32_bf16(af[i], bfr[j], acc[i][j], 0, 0, 0);
            }
        }
    }

    #pragma unroll
    for (int i = 0; i < RM; i++) {
        const int row = tm + wm + i*16 + fq*4;
        #pragma unroll
        for (int j = 0; j < 4; j++) {
            const int col = tn + wn + j*16 + fr;
            const float bv = bias[col];
            if (EPI == 3 && col >= 2048) {
                const int hh = (col - 2048) >> 6, dd = (col - 2048) & 63;
                const int batch = row >> 11, tok = row & 2047;
                u16 pk[4];
                #pragma unroll
                for (int r = 0; r < 4; r++) pk[r] = f2b(acc[i][j][r] + bv);
                *(uint2*)&C2[((long)(batch*16 + hh)*64 + dd)*2048 + tok] = *(uint2*)pk;
            } else {
                const int cw = (EPI == 3) ? 2048 : N;
                #pragma unroll
                for (int r = 0; r < 4; r++) {
                    float v = acc[i][j][r] + bv;
                    const long idx = (long)(row + r)*cw + col;
                    if (EPI == 1) v += b2f(Res[idx]);
                    if (EPI == 2) {
                        const float u = v + 0.044715f*v*v*v;
                        const float t = exp2f(u * 2.302208f);
                        v = v * t * __builtin_amdgcn_rcpf(t + 1.f);
                    }
                    C[idx] = f2b(v);
                }
            }
        }
    }
}

// ---------------------------------------------------------------------------
// Flash attention v9, causal. PAIRED q-tiles + SPLIT-KEY wave groups +
// quad-XOR K/V LDS swizzle (same both-sides trick as the GEMM).
// Block = 512 threads = 2 groups x 4 waves; (pair, head, batch) grid 16x16x2.
// ---------------------------------------------------------------------------
__global__ __launch_bounds__(512)
void attn_kernel(const u16* __restrict__ QK, const u16* __restrict__ VT,
                 u16* __restrict__ O)
{
    constexpr float CS = 0.18033688011112042f;   // 0.125 * log2(e)
    __shared__ __align__(16) u16 smem[40960];

    const int tid = threadIdx.x, wave = tid >> 6, lane = tid & 63;
    const int grp = wave >> 2, wg = wave & 3;
    const int pair = blockIdx.x, h = blockIdx.y, b = blockIdx.z;
    const int fr = lane & 15, fq = lane >> 4;
    const long qkbase = (long)b*2048*2048;
    const long vtbase = (long)(b*16 + h)*64*2048;
    const int rs = lane >> 2, cs2 = ((lane & 3) ^ ((lane >> 3) & 3)) * 8;
    const int fs = (fq ^ ((fr >> 1) & 3)) * 8;
    const int sw = (fr & 7) * 8;
    const int KsBase = grp*8192;
    const int VsBase = 16384 + grp*8192;
    u16* pw = &smem[32768 + wave*1024];

    #define ISSUE(bf, k0)                                                      \
        _Pragma("unroll")                                                      \
        for (int i = 0; i < 2; i++) {                                          \
            const int c = wg + i*4;                                            \
            const int kp = c >> 2, krb = c & 3;                                \
            gload_lds16(QK + qkbase + (long)((k0) + krb*16 + rs)*2048          \
                           + 1024 + h*64 + kp*32 + cs2,                        \
                        &smem[KsBase + (bf)*4096 + kp*2048 + krb*512]);        \
            const int vp = c & 1, vrb = c >> 1;                                \
            gload_lds16(VT + vtbase + (long)(vrb*16 + rs)*2048                 \
                           + (k0) + vp*32 + cs2,                               \
                        &smem[VsBase + (bf)*4096 + vp*2048 + vrb*512]);        \
        }

    #pragma unroll 1
    for (int which = 0; which < 2; which++) {
        const int qt = which ? pair : (31 - pair);

        bf16x8 bq[2];
        #pragma unroll
        for (int ks = 0; ks < 2; ks++)
            bq[ks] = *(const bf16x8*)&QK[qkbase + (long)(qt*64 + wg*16 + fr)*2048
                                         + h*64 + ks*32 + fq*8];

        const int q_glob = qt*64 + wg*16 + fr;
        const int q_wmin = qt*64 + wg*16;
        f32x4 o[4] = {};
        float m_i = -1e30f, l_i = 0.f;
        const int nkt = qt + 1;
        const int nit = (nkt + 1) >> 1;
        const int myn = (nkt + 1 - grp) >> 1;

        if (which) __syncthreads();
        if (grp < nkt) { ISSUE(0, grp*64) }

        for (int it = 0; it < nit; it++) {
            const int kt = 2*it + grp;
            const int k0 = kt * 64;
            const int cur = it & 1;
            __syncthreads();
            if (kt + 2 < nkt) { ISSUE(cur ^ 1, k0 + 128) }

            if (it < myn) {
                f32x4 st[4];
                #pragma unroll
                for (int mt = 0; mt < 4; mt++) st[mt] = (f32x4){0.f,0.f,0.f,0.f};
                #pragma unroll
                for (int mt = 0; mt < 4; mt++)
                    #pragma unroll
                    for (int ks = 0; ks < 2; ks++) {
                        bf16x8 ak = *(const bf16x8*)&smem[KsBase + cur*4096 + ks*2048 + (mt*16 + fr)*32 + fs];
                        st[mt] = __builtin_amdgcn_mfma_f32_16x16x32_bf16(ak, bq[ks], st[mt], 0, 0, 0);
                    }

                float mx = -1e30f;
                if (k0 + 63 > q_wmin) {
                    #pragma unroll
                    for (int mt = 0; mt < 4; mt++)
                        #pragma unroll
                        for (int r = 0; r < 4; r++) {
                            const int key = k0 + mt*16 + fq*4 + r;
                            float v = st[mt][r];
                            if (key > q_glob) v = -1e30f;
                            st[mt][r] = v;
                            mx = fmaxf(mx, v);
                        }
                } else {
                    #pragma unroll
                    for (int mt = 0; mt < 4; mt++)
                        #pragma unroll
                        for (int r = 0; r < 4; r++) mx = fmaxf(mx, st[mt][r]);
                }
                mx = fmaxf(mx, __shfl_xor(mx, 16, 64));
                mx = fmaxf(mx, __shfl_xor(mx, 32, 64));

                if (mx > m_i + 44.357f) {
                    const float alpha = exp2f((m_i - mx) * CS);
                    #pragma unroll
                    for (int dt = 0; dt < 4; dt++)
                        #pragma unroll
                        for (int r = 0; r < 4; r++) o[dt][r] *= alpha;
                    l_i *= alpha;
                    m_i = mx;
                }
                const float nms = -m_i * CS;
                float ps = 0.f;
                #pragma unroll
                for (int mt = 0; mt < 4; mt++)
                    #pragma unroll
                    for (int r = 0; r < 4; r++) {
                        const float p = exp2f(fmaf(st[mt][r], CS, nms));
                        st[mt][r] = p; ps += p;
                    }
                ps += __shfl_xor(ps, 16, 64);
                ps += __shfl_xor(ps, 32, 64);
                l_i += ps;

                #pragma unroll
                for (int mt = 0; mt < 4; mt++)
                    #pragma unroll
                    for (int d = 0; d < 2; d++) {
                        unsigned pk;
                        asm("v_cvt_pk_bf16_f32 %0, %1, %2"
                            : "=v"(pk) : "v"(st[mt][2*d]), "v"(st[mt][2*d+1]));
                        *(unsigned*)&pw[fr*64 + ((mt*16 + fq*4 + 2*d) ^ sw)] = pk;
                    }
                __asm__ volatile("" ::: "memory");
                bf16x8 bp[2];
                #pragma unroll
                for (int kk = 0; kk < 2; kk++)
                    bp[kk] = *(const bf16x8*)&pw[fr*64 + ((kk*32 + fq*8) ^ sw)];
                #pragma unroll
                for (int dt = 0; dt < 4; dt++)
                    #pragma unroll
                    for (int kk = 0; kk < 2; kk++) {
                        bf16x8 av = *(const bf16x8*)&smem[VsBase + cur*4096 + kk*2048 + (dt*16 + fr)*32 + fs];
                        o[dt] = __builtin_amdgcn_mfma_f32_16x16x32_bf16(av, bp[kk], o[dt], 0, 0, 0);
                    }
                __asm__ volatile("" ::: "memory");
            }
        }

        __syncthreads();
        float* MB = (float*)&smem[8192];
        float* ML = (float*)&smem[24576];
        if (grp == 1) {
            #pragma unroll
            for (int dt = 0; dt < 4; dt++)
                *(f32x4*)&MB[(wg*64 + lane)*16 + dt*4] = o[dt];
            if (fq == 0) {
                ML[(wg*16 + fr)*2]     = m_i;
                ML[(wg*16 + fr)*2 + 1] = l_i;
            }
        }
        __syncthreads();
        if (grp == 0) {
            const float m1 = ML[(wg*16 + fr)*2];
            const float l1 = ML[(wg*16 + fr)*2 + 1];
            const float m  = fmaxf(m_i, m1);
            const float e0 = exp2f((m_i - m) * CS);
            const float e1 = exp2f((m1  - m) * CS);
            const float rl = __builtin_amdgcn_rcpf(l_i*e0 + l1*e1);
            const long orow = (long)b*2048 + qt*64 + wg*16 + fr;
            #pragma unroll
            for (int dt = 0; dt < 4; dt++) {
                f32x4 o1 = *(const f32x4*)&MB[(wg*64 + lane)*16 + dt*4];
                u16 pk[4];
                #pragma unroll
                for (int r = 0; r < 4; r++)
                    pk[r] = f2b((o[dt][r]*e0 + o1[r]*e1) * rl);
                *(uint2*)&O[orow*1024 + h*64 + dt*16 + fq*4] = *(uint2*)pk;
            }
        }
    }
    #undef ISSUE
}

// ---------------------------------------------------------------------------
// LayerNorm over 1024 cols; bf16 in, fp32 gamma/beta; OUTF32 selects output.
// ---------------------------------------------------------------------------
template<int OUTF32>
__global__ __launch_bounds__(256)
void ln_kernel(const u16* __restrict__ X, const float* __restrict__ G,
               const float* __restrict__ B, void* __restrict__ Yv)
{
    __shared__ float red[8];
    const int tid = threadIdx.x;
    const long row = blockIdx.x;
    const u16* x = X + row*1024;
    ushort4 u = *(const ushort4*)&x[tid*4];
    const float v0 = b2f(u.x), v1 = b2f(u.y), v2 = b2f(u.z), v3 = b2f(u.w);
    float s = v0+v1+v2+v3;
    float q = v0*v0+v1*v1+v2*v2+v3*v3;
    #pragma unroll
    for (int off = 32; off >= 1; off >>= 1) {
        s += __shfl_xor(s, off, 64);
        q += __shfl_xor(q, off, 64);
    }
    const int wv = tid >> 6;
    if ((tid & 63) == 0) { red[wv*2] = s; red[wv*2+1] = q; }
    __syncthreads();
    s = red[0]+red[2]+red[4]+red[6];
    q = red[1]+red[3]+red[5]+red[7];
    const float mu = s * (1.f/1024.f);
    const float rstd = rsqrtf(fmaxf(q*(1.f/1024.f) - mu*mu, 0.f) + 1e-5f);
    float4 g4 = *(const float4*)&G[tid*4];
    float4 b4 = *(const float4*)&B[tid*4];
    const float y0 = (v0-mu)*rstd*g4.x + b4.x;
    const float y1 = (v1-mu)*rstd*g4.y + b4.y;
    const float y2 = (v2-mu)*rstd*g4.z + b4.z;
    const float y3 = (v3-mu)*rstd*g4.w + b4.w;
    if (OUTF32) {
        float4 o = make_float4(y0, y1, y2, y3);
        *(float4*)&((float*)Yv)[row*1024 + tid*4] = o;
    } else {
        ushort4 o;
        o.x = f2b(y0); o.y = f2b(y1); o.z = f2b(y2); o.w = f2b(y3);
        *(ushort4*)&((u16*)Yv)[row*1024 + tid*4] = o;
    }
}

// ---------------------------------------------------------------------------
// Workspace (48 MiB of d_ws + d_out as W1T/W2T scratch), liveness-audited:
//   Xbf [0,8) | WqkvT [8,14) | WoT [14,16) | QK [16,32) | VT [32,40) |
//   AO [40,48) | S1 [16,24) after attn | H1 [0,8) after LN1 |
//   Gbuf [8,40) FF1..FF2 | S2 [40,48) | W1T/W2T in d_out (dead before LN2)
// ---------------------------------------------------------------------------
extern "C" void kernel_launch(void* const* d_in, const int* in_sizes, int n_in,
                              void* d_out, int out_size, void* d_ws, size_t ws_size,
                              hipStream_t stream)
{
    const float* X    = (const float*)d_in[0];
    const float* Wqkv = (const float*)d_in[1];
    const float* bqkv = (const float*)d_in[2];
    const float* Wo   = (const float*)d_in[3];
    const float* bo   = (const float*)d_in[4];
    const float* W1   = (const float*)d_in[5];
    const float* b1   = (const float*)d_in[6];
    const float* W2   = (const float*)d_in[7];
    const float* b2   = (const float*)d_in[8];
    const float* g1   = (const float*)d_in[9];
    const float* be1  = (const float*)d_in[10];
    const float* g2   = (const float*)d_in[11];
    const float* be2  = (const float*)d_in[12];
    float* out = (float*)d_out;

    char* ws = (char*)d_ws;
    u16* Xbf   = (u16*)(ws + 0);
    u16* WqkvT = (u16*)(ws + 8388608);
    u16* WoT   = (u16*)(ws + 14680064);
    u16* QK    = (u16*)(ws + 16777216);        // 4096 x 2048
    u16* VT    = (u16*)(ws + 33554432);        // [2*16][64][2048]
    u16* AO    = (u16*)(ws + 41943040);
    u16* S1    = (u16*)(ws + 16777216);
    u16* H1    = (u16*)(ws + 0);
    u16* Gbuf  = (u16*)(ws + 8388608);
    u16* S2    = (u16*)(ws + 41943040);
    u16* W1T   = (u16*)d_out;
    u16* W2T   = (u16*)d_out + 4194304;

    cvt_bf16<<<4096, 256, 0, stream>>>(X, Xbf);
    cvt_transpose<<<dim3(16, 48), 256, 0, stream>>>(Wqkv, WqkvT, 1024, 3072);
    cvt_transpose<<<dim3(16, 16), 256, 0, stream>>>(Wo,   WoT,   1024, 1024);
    cvt_transpose<<<dim3(16, 64), 256, 0, stream>>>(W1,   W1T,   1024, 4096);
    cvt_transpose<<<dim3(64, 16), 256, 0, stream>>>(W2,   W2T,   4096, 1024);

    gemm_bt<3,128,0><<<dim3(32, 24), 256, 0, stream>>>(Xbf, WqkvT, bqkv, nullptr, QK, VT, 4096, 3072, 1024);
    attn_kernel<<<dim3(16, 16, 2), 512, 0, stream>>>(QK, VT, AO);
    gemm_bt<1,64,2><<<dim3(64, 8), 256, 0, stream>>>(AO, WoT, bo, Xbf, S1, nullptr, 4096, 1024, 1024);
    ln_kernel<0><<<4096, 256, 0, stream>>>(S1, g1, be1, H1);
    gemm_bt<2,128,0><<<dim3(32, 32), 256, 0, stream>>>(H1, W1T, b1, nullptr, Gbuf, nullptr, 4096, 4096, 1024);
    gemm_bt<1,64,2><<<dim3(64, 8), 256, 0, stream>>>(Gbuf, W2T, b2, H1, S2, nullptr, 4096, 1024, 4096);
    ln_kernel<1><<<4096, 256, 0, stream>>>(S2, g2, be2, out);
}

// Round 10
// 334.151 us; speedup vs baseline: 1.0936x; 1.0420x over previous
//
#include <hip/hip_runtime.h>
#include <cmath>

typedef unsigned short u16;
typedef __bf16 bf16x8 __attribute__((ext_vector_type(8)));
typedef float f32x4 __attribute__((ext_vector_type(4)));

#define DEVI __device__ __forceinline__

DEVI float b2f(u16 u){ union{unsigned int i; float f;} v; v.i=(unsigned int)u<<16; return v.f; }
DEVI u16 f2b(float f){ union{unsigned int i; float f;} v; v.f=f;
    unsigned int r=(v.i+0x7FFFu+((v.i>>16)&1u))>>16; return (u16)r; }

DEVI void gload_lds16(const u16* g, u16* l){
    __builtin_amdgcn_global_load_lds((__attribute__((address_space(1))) void*)g,
                                     (__attribute__((address_space(3))) void*)l,
                                     16, 0, 0);
}

// ---------------------------------------------------------------------------
// Fused ingest: ONE launch for X->bf16 + all 4 weight transposes (was 5
// launches; r9 budget audit showed ~100us unaccounted vs per-dispatch sums,
// launch-gap hypothesis). Block ranges: [0,4096) cvt X; [4096,4864) Wqkv;
// [4864,5120) Wo; [5120,6144) W1; [6144,7168) W2. Branch is block-uniform.
// ---------------------------------------------------------------------------
__global__ __launch_bounds__(256)
void ingest_fused(const float* __restrict__ X,    u16* __restrict__ Xbf,
                  const float* __restrict__ Wqkv, u16* __restrict__ WqkvT,
                  const float* __restrict__ Wo,   u16* __restrict__ WoT,
                  const float* __restrict__ W1,   u16* __restrict__ W1T,
                  const float* __restrict__ W2,   u16* __restrict__ W2T)
{
    __shared__ __align__(16) u16 tile[64*72];
    const int id = blockIdx.x;
    if (id < 4096) {                       // fp32 -> bf16 elementwise
        const int i = (id * 256 + threadIdx.x) * 4;
        float4 v = *(const float4*)&X[i];
        ushort4 o;
        o.x = f2b(v.x); o.y = f2b(v.y); o.z = f2b(v.z); o.w = f2b(v.w);
        *(ushort4*)&Xbf[i] = o;
        return;
    }
    const float* in; u16* out; int R, C, bx, by;
    if (id < 4864)      { const int t = id - 4096; in = Wqkv; out = WqkvT; R = 1024; C = 3072; bx = t & 15; by = t >> 4; }
    else if (id < 5120) { const int t = id - 4864; in = Wo;   out = WoT;   R = 1024; C = 1024; bx = t & 15; by = t >> 4; }
    else if (id < 6144) { const int t = id - 5120; in = W1;   out = W1T;   R = 1024; C = 4096; bx = t & 15; by = t >> 4; }
    else                { const int t = id - 6144; in = W2;   out = W2T;   R = 4096; C = 1024; bx = t & 63; by = t >> 6; }
    const int rb = bx*64, cb = by*64;
    const int t = threadIdx.x;
    const int r = t >> 3, c0 = (t & 7) * 8;
    #pragma unroll
    for (int rr = 0; rr < 2; rr++) {
        const int row = r + rr*32;
        float4 a = *(const float4*)&in[(long)(rb + row)*C + cb + c0];
        float4 b = *(const float4*)&in[(long)(rb + row)*C + cb + c0 + 4];
        u16* tp = &tile[row*72 + c0];
        tp[0]=f2b(a.x); tp[1]=f2b(a.y); tp[2]=f2b(a.z); tp[3]=f2b(a.w);
        tp[4]=f2b(b.x); tp[5]=f2b(b.y); tp[6]=f2b(b.z); tp[7]=f2b(b.w);
    }
    __syncthreads();
    #pragma unroll
    for (int rr = 0; rr < 2; rr++) {
        const int cr = r + rr*32;
        u16 tmp[8];
        #pragma unroll
        for (int j = 0; j < 8; j++) tmp[j] = tile[(c0 + j)*72 + cr];
        *(uint4*)&out[(long)(cb + cr)*R + rb + c0] = *(uint4*)tmp;
    }
}

// ---------------------------------------------------------------------------
// GEMM: C[M,N] = A[M,K] @ Bt[N,K]^T + bias. bf16 in/out, fp32 accum.
// Tile BM x 128, BK=64 (two 32-wide panels). 4 waves.
// QUAD-XOR LDS swizzle (both-sides, rule #21): staging quads contiguous
// (VMEM coalescing preserved); fragment read covers all 8 bank-groups per
// octet -> zero LDS conflicts (verified r6: SQ_LDS_BANK_CONFLICT = 0).
// PIPE=0: two-barrier serial staging (kernels at 3-4 blocks/CU, implicit
//         wave overlap hides latency).
// PIPE=2: 3-stage counted-vmcnt pipeline. r7-r9 lesson: DBUF/counted-vmcnt
//         variants all land within 2% of the 2-barrier loop at this tile
//         geometry (structure ceiling ~590 TF for N=1024 / 512-block GEMMs;
//         matches learn_hip m99/m131-m140). FF2/proj kept at the marginal
//         best (BM=64 PIPE=2, 58.0us).
// EPI: 0 = bias, 1 = bias+residual, 2 = bias+tanh-GELU,
//      3 = QKV split: cols<2048 -> C row-major (width 2048),
//          cols>=2048 (V) -> C2 = VT[b*16+h][d][tok] transposed.
// ---------------------------------------------------------------------------
template<int EPI, int BM, int PIPE>
__global__ __launch_bounds__(256)
void gemm_bt(const u16* __restrict__ A, const u16* __restrict__ Bt,
             const float* __restrict__ bias, const u16* __restrict__ Res,
             u16* __restrict__ C, u16* __restrict__ C2, int M, int N, int K)
{
    constexpr int RM = BM / 32;
    constexpr int NA = (BM / 16) * 2 / 4;
    constexpr int ASZ = BM*64, BSZ = 128*64;
    constexpr int NBUF = (PIPE == 2) ? 3 : 1;
    __shared__ __align__(16) u16 As[NBUF*ASZ];
    __shared__ __align__(16) u16 Bs[NBUF*BSZ];
    const int tid  = threadIdx.x;
    const int wave = tid >> 6, lane = tid & 63;
    const int tm = blockIdx.x * BM, tn = blockIdx.y * 128;

    // staging: lane quad a fetches row a's 64B, 16B-chunks XOR-permuted
    const int rs = lane >> 2, cs = ((lane & 3) ^ ((lane >> 3) & 3)) * 8;
    const u16* gA[NA]; u16* lA[NA];
    #pragma unroll
    for (int i = 0; i < NA; i++) {
        const int c = wave + i*4;
        const int p = c / (BM/16), rb = c % (BM/16);
        gA[i] = A + (long)(tm + rb*16 + rs)*K + p*32 + cs;
        lA[i] = As + p*(BM*32) + rb*512;
    }
    const u16* gB[4]; u16* lB[4];
    #pragma unroll
    for (int i = 0; i < 4; i++) {
        const int c = wave + i*4;
        const int p = c >> 3, rb = c & 7;
        gB[i] = Bt + (long)(tn + rb*16 + rs)*K + p*32 + cs;
        lB[i] = Bs + p*(128*32) + rb*512;
    }

    const int wm = (wave >> 1) * (BM/2), wn = (wave & 1) * 64;
    const int fr = lane & 15, fq = lane >> 4;
    const int fs = (fq ^ ((fr >> 1) & 3)) * 8;   // swizzled 16B-slot within row

    f32x4 acc[RM][4] = {};

    if constexpr (PIPE == 2) {
        constexpr int NLD = NA + 4;   // loads/thread/stage (6 @BM=64, 8 @BM=128)
        static_assert(NLD == 6 || NLD == 8, "vmcnt literal dispatch");
        const int nk = K >> 6;
        // prologue: stages 0 and 1
        #pragma unroll
        for (int i = 0; i < NA; i++) gload_lds16(gA[i], lA[i]);
        #pragma unroll
        for (int i = 0; i < 4; i++)  gload_lds16(gB[i], lB[i]);
        #pragma unroll
        for (int i = 0; i < NA; i++) gload_lds16(gA[i] + 64, lA[i] + ASZ);
        #pragma unroll
        for (int i = 0; i < 4; i++)  gload_lds16(gB[i] + 64, lB[i] + BSZ);
        int bc = 0;                       // buffer holding stage t
        for (int t = 0; t < nk; t++) {
            if (t + 1 < nk) {
                if constexpr (NLD == 8) asm volatile("s_waitcnt vmcnt(8)" ::: "memory");
                else                    asm volatile("s_waitcnt vmcnt(6)" ::: "memory");
            } else {
                asm volatile("s_waitcnt vmcnt(0)" ::: "memory");
            }
            __builtin_amdgcn_s_barrier();
            __builtin_amdgcn_sched_barrier(0);
            if (t + 2 < nk) {             // issue stage t+2 into (t+2)%3
                int bn = bc + 2; if (bn >= 3) bn -= 3;
                const int k0 = (t + 2) << 6;
                #pragma unroll
                for (int i = 0; i < NA; i++) gload_lds16(gA[i] + k0, lA[i] + bn*ASZ);
                #pragma unroll
                for (int i = 0; i < 4; i++)  gload_lds16(gB[i] + k0, lB[i] + bn*BSZ);
            }
            const u16* Ab = As + bc*ASZ;
            const u16* Bb = Bs + bc*BSZ;
            #pragma unroll
            for (int p = 0; p < 2; p++) {
                bf16x8 af[RM], bfr[4];
                #pragma unroll
                for (int i = 0; i < RM; i++)
                    af[i]  = *(const bf16x8*)&Ab[p*(BM*32) + (wm + i*16 + fr)*32 + fs];
                #pragma unroll
                for (int j = 0; j < 4; j++)
                    bfr[j] = *(const bf16x8*)&Bb[p*(128*32) + (wn + j*16 + fr)*32 + fs];
                #pragma unroll
                for (int i = 0; i < RM; i++)
                    #pragma unroll
                    for (int j = 0; j < 4; j++)
                        acc[i][j] = __builtin_amdgcn_mfma_f32_16x16x32_bf16(af[i], bfr[j], acc[i][j], 0, 0, 0);
            }
            bc++; if (bc >= 3) bc = 0;
        }
    } else {
        for (int k0 = 0; k0 < K; k0 += 64) {
            __syncthreads();
            #pragma unroll
            for (int i = 0; i < NA; i++) gload_lds16(gA[i] + k0, lA[i]);
            #pragma unroll
            for (int i = 0; i < 4; i++)  gload_lds16(gB[i] + k0, lB[i]);
            __syncthreads();
            #pragma unroll
            for (int p = 0; p < 2; p++) {
                bf16x8 af[RM], bfr[4];
                #pragma unroll
                for (int i = 0; i < RM; i++)
                    af[i]  = *(const bf16x8*)&As[p*(BM*32) + (wm + i*16 + fr)*32 + fs];
                #pragma unroll
                for (int j = 0; j < 4; j++)
                    bfr[j] = *(const bf16x8*)&Bs[p*(128*32) + (wn + j*16 + fr)*32 + fs];
                #pragma unroll
                for (int i = 0; i < RM; i++)
                    #pragma unroll
                    for (int j = 0; j < 4; j++)
                        acc[i][j] = __builtin_amdgcn_mfma_f32_16x16x32_bf16(af[i], bfr[j], acc[i][j], 0, 0, 0);
            }
        }
    }

    #pragma unroll
    for (int i = 0; i < RM; i++) {
        const int row = tm + wm + i*16 + fq*4;
        #pragma unroll
        for (int j = 0; j < 4; j++) {
            const int col = tn + wn + j*16 + fr;
            const float bv = bias[col];
            if (EPI == 3 && col >= 2048) {
                const int hh = (col - 2048) >> 6, dd = (col - 2048) & 63;
                const int batch = row >> 11, tok = row & 2047;
                u16 pk[4];
                #pragma unroll
                for (int r = 0; r < 4; r++) pk[r] = f2b(acc[i][j][r] + bv);
                *(uint2*)&C2[((long)(batch*16 + hh)*64 + dd)*2048 + tok] = *(uint2*)pk;
            } else {
                const int cw = (EPI == 3) ? 2048 : N;
                #pragma unroll
                for (int r = 0; r < 4; r++) {
                    float v = acc[i][j][r] + bv;
                    const long idx = (long)(row + r)*cw + col;
                    if (EPI == 1) v += b2f(Res[idx]);
                    if (EPI == 2) {
                        const float u = v + 0.044715f*v*v*v;
                        const float t = exp2f(u * 2.302208f);
                        v = v * t * __builtin_amdgcn_rcpf(t + 1.f);
                    }
                    C[idx] = f2b(v);
                }
            }
        }
    }
}

// ---------------------------------------------------------------------------
// Flash attention v10, causal. PAIRED q-tiles + SPLIT-KEY wave groups +
// quad-XOR K/V LDS swizzle + T5 s_setprio around MFMA clusters (attn has
// wave role-diversity: 2 independent key-groups + prefetch issue -- the
// regime where m191 measured +4-7%).
// Block = 512 threads = 2 groups x 4 waves; (pair, head, batch) grid 16x16x2.
// ---------------------------------------------------------------------------
__global__ __launch_bounds__(512)
void attn_kernel(const u16* __restrict__ QK, const u16* __restrict__ VT,
                 u16* __restrict__ O)
{
    constexpr float CS = 0.18033688011112042f;   // 0.125 * log2(e)
    __shared__ __align__(16) u16 smem[40960];

    const int tid = threadIdx.x, wave = tid >> 6, lane = tid & 63;
    const int grp = wave >> 2, wg = wave & 3;
    const int pair = blockIdx.x, h = blockIdx.y, b = blockIdx.z;
    const int fr = lane & 15, fq = lane >> 4;
    const long qkbase = (long)b*2048*2048;
    const long vtbase = (long)(b*16 + h)*64*2048;
    const int rs = lane >> 2, cs2 = ((lane & 3) ^ ((lane >> 3) & 3)) * 8;
    const int fs = (fq ^ ((fr >> 1) & 3)) * 8;
    const int sw = (fr & 7) * 8;
    const int KsBase = grp*8192;
    const int VsBase = 16384 + grp*8192;
    u16* pw = &smem[32768 + wave*1024];

    #define ISSUE(bf, k0)                                                      \
        _Pragma("unroll")                                                      \
        for (int i = 0; i < 2; i++) {                                          \
            const int c = wg + i*4;                                            \
            const int kp = c >> 2, krb = c & 3;                                \
            gload_lds16(QK + qkbase + (long)((k0) + krb*16 + rs)*2048          \
                           + 1024 + h*64 + kp*32 + cs2,                        \
                        &smem[KsBase + (bf)*4096 + kp*2048 + krb*512]);        \
            const int vp = c & 1, vrb = c >> 1;                                \
            gload_lds16(VT + vtbase + (long)(vrb*16 + rs)*2048                 \
                           + (k0) + vp*32 + cs2,                               \
                        &smem[VsBase + (bf)*4096 + vp*2048 + vrb*512]);        \
        }

    #pragma unroll 1
    for (int which = 0; which < 2; which++) {
        const int qt = which ? pair : (31 - pair);

        bf16x8 bq[2];
        #pragma unroll
        for (int ks = 0; ks < 2; ks++)
            bq[ks] = *(const bf16x8*)&QK[qkbase + (long)(qt*64 + wg*16 + fr)*2048
                                         + h*64 + ks*32 + fq*8];

        const int q_glob = qt*64 + wg*16 + fr;
        const int q_wmin = qt*64 + wg*16;
        f32x4 o[4] = {};
        float m_i = -1e30f, l_i = 0.f;
        const int nkt = qt + 1;
        const int nit = (nkt + 1) >> 1;
        const int myn = (nkt + 1 - grp) >> 1;

        if (which) __syncthreads();
        if (grp < nkt) { ISSUE(0, grp*64) }

        for (int it = 0; it < nit; it++) {
            const int kt = 2*it + grp;
            const int k0 = kt * 64;
            const int cur = it & 1;
            __syncthreads();
            if (kt + 2 < nkt) { ISSUE(cur ^ 1, k0 + 128) }

            if (it < myn) {
                f32x4 st[4];
                #pragma unroll
                for (int mt = 0; mt < 4; mt++) st[mt] = (f32x4){0.f,0.f,0.f,0.f};
                __builtin_amdgcn_s_setprio(1);
                #pragma unroll
                for (int mt = 0; mt < 4; mt++)
                    #pragma unroll
                    for (int ks = 0; ks < 2; ks++) {
                        bf16x8 ak = *(const bf16x8*)&smem[KsBase + cur*4096 + ks*2048 + (mt*16 + fr)*32 + fs];
                        st[mt] = __builtin_amdgcn_mfma_f32_16x16x32_bf16(ak, bq[ks], st[mt], 0, 0, 0);
                    }
                __builtin_amdgcn_s_setprio(0);

                float mx = -1e30f;
                if (k0 + 63 > q_wmin) {
                    #pragma unroll
                    for (int mt = 0; mt < 4; mt++)
                        #pragma unroll
                        for (int r = 0; r < 4; r++) {
                            const int key = k0 + mt*16 + fq*4 + r;
                            float v = st[mt][r];
                            if (key > q_glob) v = -1e30f;
                            st[mt][r] = v;
                            mx = fmaxf(mx, v);
                        }
                } else {
                    #pragma unroll
                    for (int mt = 0; mt < 4; mt++)
                        #pragma unroll
                        for (int r = 0; r < 4; r++) mx = fmaxf(mx, st[mt][r]);
                }
                mx = fmaxf(mx, __shfl_xor(mx, 16, 64));
                mx = fmaxf(mx, __shfl_xor(mx, 32, 64));

                if (mx > m_i + 44.357f) {
                    const float alpha = exp2f((m_i - mx) * CS);
                    #pragma unroll
                    for (int dt = 0; dt < 4; dt++)
                        #pragma unroll
                        for (int r = 0; r < 4; r++) o[dt][r] *= alpha;
                    l_i *= alpha;
                    m_i = mx;
                }
                const float nms = -m_i * CS;
                float ps = 0.f;
                #pragma unroll
                for (int mt = 0; mt < 4; mt++)
                    #pragma unroll
                    for (int r = 0; r < 4; r++) {
                        const float p = exp2f(fmaf(st[mt][r], CS, nms));
                        st[mt][r] = p; ps += p;
                    }
                ps += __shfl_xor(ps, 16, 64);
                ps += __shfl_xor(ps, 32, 64);
                l_i += ps;

                #pragma unroll
                for (int mt = 0; mt < 4; mt++)
                    #pragma unroll
                    for (int d = 0; d < 2; d++) {
                        unsigned pk;
                        asm("v_cvt_pk_bf16_f32 %0, %1, %2"
                            : "=v"(pk) : "v"(st[mt][2*d]), "v"(st[mt][2*d+1]));
                        *(unsigned*)&pw[fr*64 + ((mt*16 + fq*4 + 2*d) ^ sw)] = pk;
                    }
                __asm__ volatile("" ::: "memory");
                bf16x8 bp[2];
                #pragma unroll
                for (int kk = 0; kk < 2; kk++)
                    bp[kk] = *(const bf16x8*)&pw[fr*64 + ((kk*32 + fq*8) ^ sw)];
                __builtin_amdgcn_s_setprio(1);
                #pragma unroll
                for (int dt = 0; dt < 4; dt++)
                    #pragma unroll
                    for (int kk = 0; kk < 2; kk++) {
                        bf16x8 av = *(const bf16x8*)&smem[VsBase + cur*4096 + kk*2048 + (dt*16 + fr)*32 + fs];
                        o[dt] = __builtin_amdgcn_mfma_f32_16x16x32_bf16(av, bp[kk], o[dt], 0, 0, 0);
                    }
                __builtin_amdgcn_s_setprio(0);
                __asm__ volatile("" ::: "memory");
            }
        }

        __syncthreads();
        float* MB = (float*)&smem[8192];
        float* ML = (float*)&smem[24576];
        if (grp == 1) {
            #pragma unroll
            for (int dt = 0; dt < 4; dt++)
                *(f32x4*)&MB[(wg*64 + lane)*16 + dt*4] = o[dt];
            if (fq == 0) {
                ML[(wg*16 + fr)*2]     = m_i;
                ML[(wg*16 + fr)*2 + 1] = l_i;
            }
        }
        __syncthreads();
        if (grp == 0) {
            const float m1 = ML[(wg*16 + fr)*2];
            const float l1 = ML[(wg*16 + fr)*2 + 1];
            const float m  = fmaxf(m_i, m1);
            const float e0 = exp2f((m_i - m) * CS);
            const float e1 = exp2f((m1  - m) * CS);
            const float rl = __builtin_amdgcn_rcpf(l_i*e0 + l1*e1);
            const long orow = (long)b*2048 + qt*64 + wg*16 + fr;
            #pragma unroll
            for (int dt = 0; dt < 4; dt++) {
                f32x4 o1 = *(const f32x4*)&MB[(wg*64 + lane)*16 + dt*4];
                u16 pk[4];
                #pragma unroll
                for (int r = 0; r < 4; r++)
                    pk[r] = f2b((o[dt][r]*e0 + o1[r]*e1) * rl);
                *(uint2*)&O[orow*1024 + h*64 + dt*16 + fq*4] = *(uint2*)pk;
            }
        }
    }
    #undef ISSUE
}

// ---------------------------------------------------------------------------
// LayerNorm over 1024 cols; bf16 in, fp32 gamma/beta; OUTF32 selects output.
// ---------------------------------------------------------------------------
template<int OUTF32>
__global__ __launch_bounds__(256)
void ln_kernel(const u16* __restrict__ X, const float* __restrict__ G,
               const float* __restrict__ B, void* __restrict__ Yv)
{
    __shared__ float red[8];
    const int tid = threadIdx.x;
    const long row = blockIdx.x;
    const u16* x = X + row*1024;
    ushort4 u = *(const ushort4*)&x[tid*4];
    const float v0 = b2f(u.x), v1 = b2f(u.y), v2 = b2f(u.z), v3 = b2f(u.w);
    float s = v0+v1+v2+v3;
    float q = v0*v0+v1*v1+v2*v2+v3*v3;
    #pragma unroll
    for (int off = 32; off >= 1; off >>= 1) {
        s += __shfl_xor(s, off, 64);
        q += __shfl_xor(q, off, 64);
    }
    const int wv = tid >> 6;
    if ((tid & 63) == 0) { red[wv*2] = s; red[wv*2+1] = q; }
    __syncthreads();
    s = red[0]+red[2]+red[4]+red[6];
    q = red[1]+red[3]+red[5]+red[7];
    const float mu = s * (1.f/1024.f);
    const float rstd = rsqrtf(fmaxf(q*(1.f/1024.f) - mu*mu, 0.f) + 1e-5f);
    float4 g4 = *(const float4*)&G[tid*4];
    float4 b4 = *(const float4*)&B[tid*4];
    const float y0 = (v0-mu)*rstd*g4.x + b4.x;
    const float y1 = (v1-mu)*rstd*g4.y + b4.y;
    const float y2 = (v2-mu)*rstd*g4.z + b4.z;
    const float y3 = (v3-mu)*rstd*g4.w + b4.w;
    if (OUTF32) {
        float4 o = make_float4(y0, y1, y2, y3);
        *(float4*)&((float*)Yv)[row*1024 + tid*4] = o;
    } else {
        ushort4 o;
        o.x = f2b(y0); o.y = f2b(y1); o.z = f2b(y2); o.w = f2b(y3);
        *(ushort4*)&((u16*)Yv)[row*1024 + tid*4] = o;
    }
}

// ---------------------------------------------------------------------------
// Workspace (48 MiB of d_ws + d_out as W1T/W2T scratch), liveness-audited:
//   Xbf [0,8) | WqkvT [8,14) | WoT [14,16) | QK [16,32) | VT [32,40) |
//   AO [40,48) | S1 [16,24) after attn | H1 [0,8) after LN1 |
//   Gbuf [8,40) FF1..FF2 | S2 [40,48) | W1T/W2T in d_out (dead before LN2)
// ---------------------------------------------------------------------------
extern "C" void kernel_launch(void* const* d_in, const int* in_sizes, int n_in,
                              void* d_out, int out_size, void* d_ws, size_t ws_size,
                              hipStream_t stream)
{
    const float* X    = (const float*)d_in[0];
    const float* Wqkv = (const float*)d_in[1];
    const float* bqkv = (const float*)d_in[2];
    const float* Wo   = (const float*)d_in[3];
    const float* bo   = (const float*)d_in[4];
    const float* W1   = (const float*)d_in[5];
    const float* b1   = (const float*)d_in[6];
    const float* W2   = (const float*)d_in[7];
    const float* b2   = (const float*)d_in[8];
    const float* g1   = (const float*)d_in[9];
    const float* be1  = (const float*)d_in[10];
    const float* g2   = (const float*)d_in[11];
    const float* be2  = (const float*)d_in[12];
    float* out = (float*)d_out;

    char* ws = (char*)d_ws;
    u16* Xbf   = (u16*)(ws + 0);
    u16* WqkvT = (u16*)(ws + 8388608);
    u16* WoT   = (u16*)(ws + 14680064);
    u16* QK    = (u16*)(ws + 16777216);        // 4096 x 2048
    u16* VT    = (u16*)(ws + 33554432);        // [2*16][64][2048]
    u16* AO    = (u16*)(ws + 41943040);
    u16* S1    = (u16*)(ws + 16777216);
    u16* H1    = (u16*)(ws + 0);
    u16* Gbuf  = (u16*)(ws + 8388608);
    u16* S2    = (u16*)(ws + 41943040);
    u16* W1T   = (u16*)d_out;
    u16* W2T   = (u16*)d_out + 4194304;

    ingest_fused<<<7168, 256, 0, stream>>>(X, Xbf, Wqkv, WqkvT, Wo, WoT, W1, W1T, W2, W2T);

    gemm_bt<3,128,0><<<dim3(32, 24), 256, 0, stream>>>(Xbf, WqkvT, bqkv, nullptr, QK, VT, 4096, 3072, 1024);
    attn_kernel<<<dim3(16, 16, 2), 512, 0, stream>>>(QK, VT, AO);
    gemm_bt<1,64,2><<<dim3(64, 8), 256, 0, stream>>>(AO, WoT, bo, Xbf, S1, nullptr, 4096, 1024, 1024);
    ln_kernel<0><<<4096, 256, 0, stream>>>(S1, g1, be1, H1);
    gemm_bt<2,128,0><<<dim3(32, 32), 256, 0, stream>>>(H1, W1T, b1, nullptr, Gbuf, nullptr, 4096, 4096, 1024);
    gemm_bt<1,64,2><<<dim3(64, 8), 256, 0, stream>>>(Gbuf, W2T, b2, H1, S2, nullptr, 4096, 1024, 4096);
    ln_kernel<1><<<4096, 256, 0, stream>>>(S2, g2, be2, out);
}